// Round 5
// baseline (254.595 us; speedup 1.0000x reference)
//
#include <hip/hip_runtime.h>
#include <hip/hip_bf16.h>
#include <cstdint>
#include <cstddef>

#define N_FEAT 512
#define N_HID 64
#define N_CLASS 16
#define N_CLUSTER 32
#define NPART 8          // privatized histogram partitions

typedef short short8 __attribute__((ext_vector_type(8)));
typedef float floatx4 __attribute__((ext_vector_type(4)));

__device__ __forceinline__ short f2bf(float f) {
  __hip_bfloat16 h = __float2bfloat16(f);
  return *reinterpret_cast<short*>(&h);
}

// ---------------- packed degree/count histogram: one u64 atomic per edge ----------------
__global__ void k_degcnt2(const int* __restrict__ col, const float* __restrict__ w,
                          unsigned long long* __restrict__ hist, int H, int E) {
  int e = blockIdx.x * 256 + threadIdx.x;
  if (e >= E) return;
  int p = blockIdx.x & (NPART - 1);
  int c = col[e];
  unsigned long long fx = (unsigned long long)__float2uint_rn(w[e] * 16777216.0f);
  atomicAdd(&hist[(size_t)p * H + c], (1ull << 40) | fx);
}

// ---------------- fold partitions -> cnt, dinv ----------------
__global__ void k_reduce(const unsigned long long* __restrict__ hist, int H,
                         int* __restrict__ cnt, float* __restrict__ dinv, int n) {
  int i = blockIdx.x * 256 + threadIdx.x;
  if (i >= n) return;
  unsigned long long tot = 0;
  #pragma unroll
  for (int p = 0; p < NPART; ++p) tot += hist[(size_t)p * H + i];
  int c = (int)(tot >> 40);
  float wsum = (float)(tot & ((1ull << 40) - 1)) * 5.9604644775390625e-08f; // 2^-24
  cnt[i] = c;
  dinv[i] = rsqrtf(1.0f + wsum);
}

// ---------------- two-level exclusive scan of cnt -> off ----------------
__global__ __launch_bounds__(256) void k_scan1(const int* __restrict__ cnt,
                                               int* __restrict__ off,
                                               int* __restrict__ bsum, int n) {
  __shared__ int sh[256];
  int t = threadIdx.x;
  int i = blockIdx.x * 256 + t;
  int v = (i < n) ? cnt[i] : 0;
  sh[t] = v;
  __syncthreads();
  #pragma unroll
  for (int d = 1; d < 256; d <<= 1) {
    int x = 0;
    if (t >= d) x = sh[t - d];
    __syncthreads();
    if (t >= d) sh[t] += x;
    __syncthreads();
  }
  if (i < n) off[i] = sh[t] - v;
  if (t == 255) bsum[blockIdx.x] = sh[255];
}

__global__ __launch_bounds__(256) void k_scan2(const int* __restrict__ bsum,
                                               int* __restrict__ bsum2, int nb) {
  __shared__ int sh[256];
  int t = threadIdx.x;
  int v = (t < nb) ? bsum[t] : 0;
  sh[t] = v;
  __syncthreads();
  #pragma unroll
  for (int d = 1; d < 256; d <<= 1) {
    int x = 0;
    if (t >= d) x = sh[t - d];
    __syncthreads();
    if (t >= d) sh[t] += x;
    __syncthreads();
  }
  if (t < nb) bsum2[t] = sh[t] - v;
}

__global__ void k_scan3_initcur(int* __restrict__ off, const int* __restrict__ bsum2,
                                const unsigned long long* __restrict__ hist, int H,
                                int* __restrict__ cur, int n, int E) {
  int i = blockIdx.x * 256 + threadIdx.x;
  if (i < n) {
    int o = off[i] + bsum2[blockIdx.x];
    off[i] = o;
    int running = o;
    #pragma unroll
    for (int p = 0; p < NPART; ++p) {
      cur[(size_t)p * H + i] = running;
      running += (int)(hist[(size_t)p * H + i] >> 40);
    }
  }
  if (i == 0) off[n] = E;
}

// ---------------- fill CSR slots: single 8B (src, coef) store per edge ----------------
__global__ void k_fill2(const int* __restrict__ rowi, const int* __restrict__ coli,
                        const float* __restrict__ w, const float* __restrict__ dinv,
                        int* __restrict__ cur, int H,
                        int2* __restrict__ pairs, int E) {
  int e = blockIdx.x * 256 + threadIdx.x;
  if (e >= E) return;
  int p = blockIdx.x & (NPART - 1);       // must match k_degcnt2's mapping
  int r = rowi[e], c = coli[e];
  int pos = atomicAdd(&cur[(size_t)p * H + c], 1);
  pairs[pos] = make_int2(r, __float_as_int(dinv[r] * w[e] * dinv[c]));
}

// ---------------- W[K][64] fp32 -> Bt[64][K+8] bf16 (transposed, padded) ----------------
__global__ void k_prepB(const float* __restrict__ W, short* __restrict__ Bt,
                        int K, int ncol) {
  int idx = blockIdx.x * 256 + threadIdx.x;
  int kg = K >> 3;
  if (idx >= ncol * kg) return;
  int c = idx / kg, g = idx - c * kg;
  short8 v;
  #pragma unroll
  for (int j = 0; j < 8; ++j) v[j] = f2bf(W[(size_t)(g * 8 + j) * ncol + c]);
  *(short8*)(Bt + (size_t)c * (K + 8) + g * 8) = v;
}

// ---------------- MFMA GEMM: C[M,64] = act(A[M,K]) @ B[K,64] ----------------
// A staged through LDS in fragment order (coalesced global loads -> ds_write
// into per-lane slots), B fragments direct from pre-transposed bf16 Bt (L2-hot).
// LDS slot layout: slot = wave*64+lane, 20 floats/slot (16 used + 4 pad so
// slot stride = 80B -> bank-start 20*l%32 has period 32 -> 2-way max on b128).
template<int K, bool RELU>
__global__ __launch_bounds__(256) void k_mfma(
    const float* __restrict__ A, const short* __restrict__ Bt,
    float* __restrict__ C, int M) {
  constexpr int BS = K + 8;
  __shared__ float As[256 * 20];           // 20 KB
  const int t = threadIdx.x;
  const int lane = t & 63;
  const int wid = t >> 6;
  const int row0 = blockIdx.x * 64;
  const short* bbase = Bt + (size_t)(lane & 15) * BS + (lane >> 4) * 8;

  floatx4 acc[4];
  #pragma unroll
  for (int j = 0; j < 4; ++j) acc[j] = (floatx4){0.f, 0.f, 0.f, 0.f};

  const int myslot = wid * 64 + lane;

  for (int kc = 0; kc < K; kc += 64) {
    // ---- stage: 64 rows x 64 k, coalesced, into fragment-order slots ----
    float4 v[4];
    int srow[4], sk4[4];
    #pragma unroll
    for (int i = 0; i < 4; ++i) {
      int f = t + i * 256;                 // 0..1023
      int row = f >> 4, k4 = f & 15;       // k = 4*k4 .. +3 within chunk
      srow[i] = row; sk4[i] = k4;
      int grow = row0 + row;
      if (grow >= M) grow = M - 1;
      v[i] = *(const float4*)&A[(size_t)grow * K + kc + k4 * 4];
      if (RELU) {
        v[i].x = fmaxf(v[i].x, 0.f); v[i].y = fmaxf(v[i].y, 0.f);
        v[i].z = fmaxf(v[i].z, 0.f); v[i].w = fmaxf(v[i].w, 0.f);
      }
    }
    __syncthreads();                       // protect prev-iter reads
    #pragma unroll
    for (int i = 0; i < 4; ++i) {
      int row = srow[i], k4 = sk4[i];
      int slot = (row >> 4) * 64 + (row & 15) + (((k4 >> 1) & 3) << 4);
      int idx = (k4 >> 3) * 2 + (k4 & 1);  // float4 index within slot
      *(float4*)&As[slot * 20 + idx * 4] = v[i];
    }
    __syncthreads();
    // ---- compute: 2 x (a-frag from LDS, 4 MFMA with b-frags from global) ----
    #pragma unroll
    for (int kq = 0; kq < 2; ++kq) {
      float4 f0 = *(const float4*)&As[myslot * 20 + kq * 8];
      float4 f1 = *(const float4*)&As[myslot * 20 + kq * 8 + 4];
      short8 af;
      af[0] = f2bf(f0.x); af[1] = f2bf(f0.y); af[2] = f2bf(f0.z); af[3] = f2bf(f0.w);
      af[4] = f2bf(f1.x); af[5] = f2bf(f1.y); af[6] = f2bf(f1.z); af[7] = f2bf(f1.w);
      const short* bk = bbase + kc + kq * 32;
      #pragma unroll
      for (int j = 0; j < 4; ++j) {
        short8 bf = *(const short8*)(bk + (size_t)j * 16 * BS);
        acc[j] = __builtin_amdgcn_mfma_f32_16x16x32_bf16(af, bf, acc[j], 0, 0, 0);
      }
    }
  }

  const int srowo = row0 + wid * 16 + (lane >> 4) * 4;
  const int scol = lane & 15;
  #pragma unroll
  for (int i = 0; i < 4; ++i) {
    int rr = srowo + i;
    if (rr < M) {
      #pragma unroll
      for (int j = 0; j < 4; ++j)
        C[(size_t)rr * 64 + j * 16 + scol] = acc[j][i];
    }
  }
}

// ---------------- gather conv: one wave per node, lane = feature dim ----------------
__global__ __launch_bounds__(256) void k_gather(
    const int* __restrict__ off, const int2* __restrict__ pairs,
    const float* __restrict__ dinv,
    const float* __restrict__ xw, const float* __restrict__ bias,
    float* __restrict__ h, int n) {
  int gid = blockIdx.x * 256 + threadIdx.x;
  int c = gid >> 6, lane = gid & 63;
  if (c >= n) return;
  float s = dinv[c]; s *= s;
  float acc = fmaf(xw[(size_t)c * 64 + lane], s, bias[lane]);
  int i = off[c], end = off[c + 1];
  for (; i + 3 < end; i += 4) {
    int2 p0 = pairs[i], p1 = pairs[i + 1], p2 = pairs[i + 2], p3 = pairs[i + 3];
    float v0 = xw[(size_t)p0.x * 64 + lane];
    float v1 = xw[(size_t)p1.x * 64 + lane];
    float v2 = xw[(size_t)p2.x * 64 + lane];
    float v3 = xw[(size_t)p3.x * 64 + lane];
    acc = fmaf(v0, __int_as_float(p0.y), acc);
    acc = fmaf(v1, __int_as_float(p1.y), acc);
    acc = fmaf(v2, __int_as_float(p2.y), acc);
    acc = fmaf(v3, __int_as_float(p3.y), acc);
  }
  for (; i < end; ++i) {
    int2 p = pairs[i];
    acc = fmaf(xw[(size_t)p.x * 64 + lane], __int_as_float(p.y), acc);
  }
  h[(size_t)c * 64 + lane] = acc;
}

// ---------------- fused FC head ----------------
__global__ __launch_bounds__(256) void k_fc(
    const float* __restrict__ h,
    const float* __restrict__ fW1, const float* __restrict__ fb1,
    const float* __restrict__ fW2, const float* __restrict__ fb2,
    float* __restrict__ out, int M) {
  __shared__ float Hs[64][68];
  __shared__ float Ws[64][48];
  __shared__ float bs[48];
  const int t = threadIdx.x;
  const int row0 = blockIdx.x * 64;
  #pragma unroll
  for (int i = 0; i < 4; ++i) {
    int f = t + i * 256;
    int r = f >> 4, k4 = f & 15;
    int rr = row0 + r;
    float4 v = make_float4(0.f, 0.f, 0.f, 0.f);
    if (rr < M) v = *(const float4*)&h[(size_t)rr * 64 + k4 * 4];
    *(float4*)&Hs[r][k4 * 4] = v;
  }
  for (int f = t; f < 64 * 48; f += 256) {
    int k = f / 48, c = f - k * 48;
    Ws[k][c] = (c < 16) ? fW1[k * 16 + c] : fW2[k * 32 + (c - 16)];
  }
  if (t < 48) bs[t] = (t < 16) ? fb1[t] : fb2[t - 16];
  __syncthreads();
  const int tr = t >> 4, tc = t & 15;
  float acc[4][3] = {{0.f}};
  #pragma unroll 8
  for (int k = 0; k < 64; ++k) {
    float a[4], b[3];
    #pragma unroll
    for (int i = 0; i < 4; ++i) a[i] = Hs[tr * 4 + i][k];
    #pragma unroll
    for (int j = 0; j < 3; ++j) b[j] = Ws[k][tc * 3 + j];
    #pragma unroll
    for (int i = 0; i < 4; ++i)
      #pragma unroll
      for (int j = 0; j < 3; ++j) acc[i][j] = fmaf(a[i], b[j], acc[i][j]);
  }
  #pragma unroll
  for (int i = 0; i < 4; ++i) {
    int rr = row0 + tr * 4 + i;
    if (rr >= M) continue;
    #pragma unroll
    for (int j = 0; j < 3; ++j) {
      int c = tc * 3 + j;
      float v = acc[i][j] + bs[c];
      if (c < 16) out[(size_t)rr * 16 + c] = v;
      else out[(size_t)M * 16 + (size_t)rr * 32 + (c - 16)] = v;
    }
  }
}

extern "C" void kernel_launch(void* const* d_in, const int* in_sizes, int n_in,
                              void* d_out, int out_size, void* d_ws, size_t ws_size,
                              hipStream_t stream) {
  const float* x    = (const float*)d_in[0];
  const int*   ei   = (const int*)d_in[1];
  const float* ew   = (const float*)d_in[2];
  const float* W1   = (const float*)d_in[3];
  const float* b1   = (const float*)d_in[4];
  const float* W2   = (const float*)d_in[5];
  const float* b2   = (const float*)d_in[6];
  const float* fW1  = (const float*)d_in[7];
  const float* fb1  = (const float*)d_in[8];
  const float* fW2  = (const float*)d_in[9];
  const float* fb2  = (const float*)d_in[10];
  float* out = (float*)d_out;

  const int N = in_sizes[0] / N_FEAT;
  const int E = in_sizes[2];
  const int H = (N + 63) & ~63;
  const int* row = ei;
  const int* col = ei + E;

  char* ws = (char*)d_ws;
  float*              dinv = (float*)(ws + 0x000000);              // N f
  int*                cnt  = (int*)  (ws + 0x040000);              // N i
  int*                off  = (int*)  (ws + 0x080000);              // N+1 i
  int*                bsum = (int*)  (ws + 0x0C0000);
  int*                bsum2= (int*)  (ws + 0x0C1000);
  short*              Bt1  = (short*)(ws + 0x0C8000);              // 64*520 bf16
  short*              Bt2  = (short*)(ws + 0x0DA000);              // 64*72 bf16
  unsigned long long* hist = (unsigned long long*)(ws + 0x100000); // 8*H u64 (3.2MB)
  int*                cur  = (int*)  (ws + 0x500000);              // 8*H i (1.6MB)
  int2*               pairs= (int2*) (ws + 0x6C0000);              // E int2 (6.4MB)
  float*              bufA = (float*)(ws + 0xD40000);              // N*64 f (12.8MB)
  float*              bufB = (float*)(ws + 0x1980000);             // N*64 f (12.8MB)

  const int nbN  = (N + 255) / 256;
  const int nbE  = (E + 255) / 256;
  const int nbG  = (N + 63) / 64;
  const int nbW  = (N * 64 + 255) / 256;

  // ---- weight pre-transpose (bf16) ----
  k_prepB<<<16, 256, 0, stream>>>(W1, Bt1, N_FEAT, 64);
  k_prepB<<<2,  256, 0, stream>>>(W2, Bt2, N_HID, 64);

  // ---- CSR build (shared by both conv layers) ----
  hipMemsetAsync(hist, 0, (size_t)NPART * H * 8, stream);
  k_degcnt2<<<nbE, 256, 0, stream>>>(col, ew, hist, H, E);
  k_reduce <<<nbN, 256, 0, stream>>>(hist, H, cnt, dinv, N);
  k_scan1  <<<nbN, 256, 0, stream>>>(cnt, off, bsum, N);
  k_scan2  <<<1,   256, 0, stream>>>(bsum, bsum2, nbN);
  k_scan3_initcur<<<nbN, 256, 0, stream>>>(off, bsum2, hist, H, cur, N, E);
  k_fill2  <<<nbE, 256, 0, stream>>>(row, col, ew, dinv, cur, H, pairs, E);

  // ---- layer 1 ----
  k_mfma<N_FEAT, false><<<nbG, 256, 0, stream>>>(x, Bt1, bufA, N);
  k_gather<<<nbW, 256, 0, stream>>>(off, pairs, dinv, bufA, b1, bufB, N);

  // ---- layer 2 (relu fused into staging) ----
  k_mfma<N_HID, true><<<nbG, 256, 0, stream>>>(bufB, Bt2, bufA, N);
  k_gather<<<nbW, 256, 0, stream>>>(off, pairs, dinv, bufA, b2, bufB, N);

  // ---- FC heads ----
  k_fc<<<nbG, 256, 0, stream>>>(bufB, fW1, fb1, fW2, fb2, out, N);
}

// Round 6
// 228.782 us; speedup vs baseline: 1.1128x; 1.1128x over previous
//
#include <hip/hip_runtime.h>
#include <hip/hip_bf16.h>
#include <cstdint>
#include <cstddef>

#define N_FEAT 512
#define N_HID 64
#define N_CLASS 16
#define N_CLUSTER 32
#define NPART 8          // privatized histogram partitions

typedef short short8 __attribute__((ext_vector_type(8)));
typedef float floatx4 __attribute__((ext_vector_type(4)));

__device__ __forceinline__ short f2bf(float f) {
  __hip_bfloat16 h = __float2bfloat16(f);
  return *reinterpret_cast<short*>(&h);
}

// ---------------- packed degree/count histogram: one u64 atomic per edge ----------------
__global__ void k_degcnt2(const int* __restrict__ col, const float* __restrict__ w,
                          unsigned long long* __restrict__ hist, int H, int E) {
  int e = blockIdx.x * 256 + threadIdx.x;
  if (e >= E) return;
  int p = blockIdx.x & (NPART - 1);
  int c = col[e];
  unsigned long long fx = (unsigned long long)__float2uint_rn(w[e] * 16777216.0f);
  atomicAdd(&hist[(size_t)p * H + c], (1ull << 40) | fx);
}

// ---------------- fold partitions -> cnt, dinv ----------------
__global__ void k_reduce(const unsigned long long* __restrict__ hist, int H,
                         int* __restrict__ cnt, float* __restrict__ dinv, int n) {
  int i = blockIdx.x * 256 + threadIdx.x;
  if (i >= n) return;
  unsigned long long tot = 0;
  #pragma unroll
  for (int p = 0; p < NPART; ++p) tot += hist[(size_t)p * H + i];
  int c = (int)(tot >> 40);
  float wsum = (float)(tot & ((1ull << 40) - 1)) * 5.9604644775390625e-08f; // 2^-24
  cnt[i] = c;
  dinv[i] = rsqrtf(1.0f + wsum);
}

// ---------------- two-level exclusive scan of cnt -> off ----------------
__global__ __launch_bounds__(256) void k_scan1(const int* __restrict__ cnt,
                                               int* __restrict__ off,
                                               int* __restrict__ bsum, int n) {
  __shared__ int sh[256];
  int t = threadIdx.x;
  int i = blockIdx.x * 256 + t;
  int v = (i < n) ? cnt[i] : 0;
  sh[t] = v;
  __syncthreads();
  #pragma unroll
  for (int d = 1; d < 256; d <<= 1) {
    int x = 0;
    if (t >= d) x = sh[t - d];
    __syncthreads();
    if (t >= d) sh[t] += x;
    __syncthreads();
  }
  if (i < n) off[i] = sh[t] - v;
  if (t == 255) bsum[blockIdx.x] = sh[255];
}

__global__ __launch_bounds__(256) void k_scan2(const int* __restrict__ bsum,
                                               int* __restrict__ bsum2, int nb) {
  __shared__ int sh[256];
  int t = threadIdx.x;
  int v = (t < nb) ? bsum[t] : 0;
  sh[t] = v;
  __syncthreads();
  #pragma unroll
  for (int d = 1; d < 256; d <<= 1) {
    int x = 0;
    if (t >= d) x = sh[t - d];
    __syncthreads();
    if (t >= d) sh[t] += x;
    __syncthreads();
  }
  if (t < nb) bsum2[t] = sh[t] - v;
}

__global__ void k_scan3_initcur(int* __restrict__ off, const int* __restrict__ bsum2,
                                const unsigned long long* __restrict__ hist, int H,
                                int* __restrict__ cur, int n, int E) {
  int i = blockIdx.x * 256 + threadIdx.x;
  if (i < n) {
    int o = off[i] + bsum2[blockIdx.x];
    off[i] = o;
    int running = o;
    #pragma unroll
    for (int p = 0; p < NPART; ++p) {
      cur[(size_t)p * H + i] = running;
      running += (int)(hist[(size_t)p * H + i] >> 40);
    }
  }
  if (i == 0) off[n] = E;
}

// ---------------- fill CSR slots: single 8B (src, coef) store per edge ----------------
__global__ void k_fill2(const int* __restrict__ rowi, const int* __restrict__ coli,
                        const float* __restrict__ w, const float* __restrict__ dinv,
                        int* __restrict__ cur, int H,
                        int2* __restrict__ pairs, int E) {
  int e = blockIdx.x * 256 + threadIdx.x;
  if (e >= E) return;
  int p = blockIdx.x & (NPART - 1);       // must match k_degcnt2's mapping
  int r = rowi[e], c = coli[e];
  int pos = atomicAdd(&cur[(size_t)p * H + c], 1);
  pairs[pos] = make_int2(r, __float_as_int(dinv[r] * w[e] * dinv[c]));
}

// ---------------- W[K][64] fp32 -> Bt[64][K+8] bf16 (transposed, padded) ----------------
__global__ void k_prepB(const float* __restrict__ W, short* __restrict__ Bt,
                        int K, int ncol) {
  int idx = blockIdx.x * 256 + threadIdx.x;
  int kg = K >> 3;
  if (idx >= ncol * kg) return;
  int c = idx / kg, g = idx - c * kg;
  short8 v;
  #pragma unroll
  for (int j = 0; j < 8; ++j) v[j] = f2bf(W[(size_t)(g * 8 + j) * ncol + c]);
  *(short8*)(Bt + (size_t)c * (K + 8) + g * 8) = v;
}

// ---------------- MFMA GEMM: C[M,64] = act(A[M,K]) @ B[K,64] ----------------
// One wave per 16-row tile, no LDS, no barriers. Explicit P-deep rotating
// register pipeline keeps ~P KB of A + B loads in flight per wave to cover
// ~900cy memory latency (round 4/5 were concurrency-starved at 48 VGPR).
template<int K, bool RELU>
__global__ __launch_bounds__(64) void k_mfma(
    const float* __restrict__ A, const short* __restrict__ Bt,
    float* __restrict__ C, int M) {
  constexpr int BS = K + 8;
  constexpr int NSTEP = K / 32;
  constexpr int P = (NSTEP < 4) ? NSTEP : 4;
  const int lane = threadIdx.x & 63;
  const int rbase = blockIdx.x * 16;
  int r = rbase + (lane & 15);
  if (r >= M) r = M - 1;                    // only its own D-row is garbage
  const int klo = (lane >> 4) * 8;
  const float* arow = A + (size_t)r * K + klo;
  const short* bbase = Bt + (size_t)(lane & 15) * BS + klo;

  float4 pa0[P], pa1[P];
  short8 pb[P][4];
  #pragma unroll
  for (int s = 0; s < P; ++s) {
    pa0[s] = *(const float4*)(arow + s * 32);
    pa1[s] = *(const float4*)(arow + s * 32 + 4);
    #pragma unroll
    for (int j = 0; j < 4; ++j)
      pb[s][j] = *(const short8*)(bbase + (size_t)j * 16 * BS + s * 32);
  }

  floatx4 acc[4];
  #pragma unroll
  for (int j = 0; j < 4; ++j) acc[j] = (floatx4){0.f, 0.f, 0.f, 0.f};

  #pragma unroll
  for (int s = 0; s < NSTEP; ++s) {
    const int sl = s % P;                   // constant after unroll
    float4 a0 = pa0[sl], a1 = pa1[sl];
    short8 b0 = pb[sl][0], b1 = pb[sl][1], b2 = pb[sl][2], b3 = pb[sl][3];
    if (s + P < NSTEP) {                    // refill slot
      pa0[sl] = *(const float4*)(arow + (s + P) * 32);
      pa1[sl] = *(const float4*)(arow + (s + P) * 32 + 4);
      #pragma unroll
      for (int j = 0; j < 4; ++j)
        pb[sl][j] = *(const short8*)(bbase + (size_t)j * 16 * BS + (s + P) * 32);
    }
    if (RELU) {
      a0.x = fmaxf(a0.x, 0.f); a0.y = fmaxf(a0.y, 0.f);
      a0.z = fmaxf(a0.z, 0.f); a0.w = fmaxf(a0.w, 0.f);
      a1.x = fmaxf(a1.x, 0.f); a1.y = fmaxf(a1.y, 0.f);
      a1.z = fmaxf(a1.z, 0.f); a1.w = fmaxf(a1.w, 0.f);
    }
    short8 af;
    af[0] = f2bf(a0.x); af[1] = f2bf(a0.y); af[2] = f2bf(a0.z); af[3] = f2bf(a0.w);
    af[4] = f2bf(a1.x); af[5] = f2bf(a1.y); af[6] = f2bf(a1.z); af[7] = f2bf(a1.w);
    acc[0] = __builtin_amdgcn_mfma_f32_16x16x32_bf16(af, b0, acc[0], 0, 0, 0);
    acc[1] = __builtin_amdgcn_mfma_f32_16x16x32_bf16(af, b1, acc[1], 0, 0, 0);
    acc[2] = __builtin_amdgcn_mfma_f32_16x16x32_bf16(af, b2, acc[2], 0, 0, 0);
    acc[3] = __builtin_amdgcn_mfma_f32_16x16x32_bf16(af, b3, acc[3], 0, 0, 0);
  }

  const int srow = rbase + (lane >> 4) * 4;
  const int scol = lane & 15;
  #pragma unroll
  for (int i = 0; i < 4; ++i) {
    int rr = srow + i;
    if (rr < M) {
      #pragma unroll
      for (int j = 0; j < 4; ++j)
        C[(size_t)rr * 64 + j * 16 + scol] = acc[j][i];
    }
  }
}

// ---------------- gather conv: one wave per node, lane = feature dim ----------------
__global__ __launch_bounds__(256) void k_gather(
    const int* __restrict__ off, const int2* __restrict__ pairs,
    const float* __restrict__ dinv,
    const float* __restrict__ xw, const float* __restrict__ bias,
    float* __restrict__ h, int n) {
  int gid = blockIdx.x * 256 + threadIdx.x;
  int c = gid >> 6, lane = gid & 63;
  if (c >= n) return;
  float s = dinv[c]; s *= s;
  float acc = fmaf(xw[(size_t)c * 64 + lane], s, bias[lane]);
  int i = off[c], end = off[c + 1];
  for (; i + 3 < end; i += 4) {
    int2 p0 = pairs[i], p1 = pairs[i + 1], p2 = pairs[i + 2], p3 = pairs[i + 3];
    float v0 = xw[(size_t)p0.x * 64 + lane];
    float v1 = xw[(size_t)p1.x * 64 + lane];
    float v2 = xw[(size_t)p2.x * 64 + lane];
    float v3 = xw[(size_t)p3.x * 64 + lane];
    acc = fmaf(v0, __int_as_float(p0.y), acc);
    acc = fmaf(v1, __int_as_float(p1.y), acc);
    acc = fmaf(v2, __int_as_float(p2.y), acc);
    acc = fmaf(v3, __int_as_float(p3.y), acc);
  }
  for (; i < end; ++i) {
    int2 p = pairs[i];
    acc = fmaf(xw[(size_t)p.x * 64 + lane], __int_as_float(p.y), acc);
  }
  h[(size_t)c * 64 + lane] = acc;
}

// ---------------- fused FC head ----------------
__global__ __launch_bounds__(256) void k_fc(
    const float* __restrict__ h,
    const float* __restrict__ fW1, const float* __restrict__ fb1,
    const float* __restrict__ fW2, const float* __restrict__ fb2,
    float* __restrict__ out, int M) {
  __shared__ float Hs[64][68];
  __shared__ float Ws[64][48];
  __shared__ float bs[48];
  const int t = threadIdx.x;
  const int row0 = blockIdx.x * 64;
  #pragma unroll
  for (int i = 0; i < 4; ++i) {
    int f = t + i * 256;
    int r = f >> 4, k4 = f & 15;
    int rr = row0 + r;
    float4 v = make_float4(0.f, 0.f, 0.f, 0.f);
    if (rr < M) v = *(const float4*)&h[(size_t)rr * 64 + k4 * 4];
    *(float4*)&Hs[r][k4 * 4] = v;
  }
  for (int f = t; f < 64 * 48; f += 256) {
    int k = f / 48, c = f - k * 48;
    Ws[k][c] = (c < 16) ? fW1[k * 16 + c] : fW2[k * 32 + (c - 16)];
  }
  if (t < 48) bs[t] = (t < 16) ? fb1[t] : fb2[t - 16];
  __syncthreads();
  const int tr = t >> 4, tc = t & 15;
  float acc[4][3] = {{0.f}};
  #pragma unroll 8
  for (int k = 0; k < 64; ++k) {
    float a[4], b[3];
    #pragma unroll
    for (int i = 0; i < 4; ++i) a[i] = Hs[tr * 4 + i][k];
    #pragma unroll
    for (int j = 0; j < 3; ++j) b[j] = Ws[k][tc * 3 + j];
    #pragma unroll
    for (int i = 0; i < 4; ++i)
      #pragma unroll
      for (int j = 0; j < 3; ++j) acc[i][j] = fmaf(a[i], b[j], acc[i][j]);
  }
  #pragma unroll
  for (int i = 0; i < 4; ++i) {
    int rr = row0 + tr * 4 + i;
    if (rr >= M) continue;
    #pragma unroll
    for (int j = 0; j < 3; ++j) {
      int c = tc * 3 + j;
      float v = acc[i][j] + bs[c];
      if (c < 16) out[(size_t)rr * 16 + c] = v;
      else out[(size_t)M * 16 + (size_t)rr * 32 + (c - 16)] = v;
    }
  }
}

extern "C" void kernel_launch(void* const* d_in, const int* in_sizes, int n_in,
                              void* d_out, int out_size, void* d_ws, size_t ws_size,
                              hipStream_t stream) {
  const float* x    = (const float*)d_in[0];
  const int*   ei   = (const int*)d_in[1];
  const float* ew   = (const float*)d_in[2];
  const float* W1   = (const float*)d_in[3];
  const float* b1   = (const float*)d_in[4];
  const float* W2   = (const float*)d_in[5];
  const float* b2   = (const float*)d_in[6];
  const float* fW1  = (const float*)d_in[7];
  const float* fb1  = (const float*)d_in[8];
  const float* fW2  = (const float*)d_in[9];
  const float* fb2  = (const float*)d_in[10];
  float* out = (float*)d_out;

  const int N = in_sizes[0] / N_FEAT;
  const int E = in_sizes[2];
  const int H = (N + 63) & ~63;
  const int* row = ei;
  const int* col = ei + E;

  char* ws = (char*)d_ws;
  float*              dinv = (float*)(ws + 0x000000);              // N f
  int*                cnt  = (int*)  (ws + 0x040000);              // N i
  int*                off  = (int*)  (ws + 0x080000);              // N+1 i
  int*                bsum = (int*)  (ws + 0x0C0000);
  int*                bsum2= (int*)  (ws + 0x0C1000);
  short*              Bt1  = (short*)(ws + 0x0C8000);              // 64*520 bf16
  short*              Bt2  = (short*)(ws + 0x0DA000);              // 64*72 bf16
  unsigned long long* hist = (unsigned long long*)(ws + 0x100000); // 8*H u64 (3.2MB)
  int*                cur  = (int*)  (ws + 0x500000);              // 8*H i (1.6MB)
  int2*               pairs= (int2*) (ws + 0x6C0000);              // E int2 (6.4MB)
  float*              bufA = (float*)(ws + 0xD40000);              // N*64 f (12.8MB)
  float*              bufB = (float*)(ws + 0x1980000);             // N*64 f (12.8MB)

  const int nbN  = (N + 255) / 256;
  const int nbE  = (E + 255) / 256;
  const int nbT  = (N + 15) / 16;          // one wave (16 rows) per block
  const int nbG  = (N + 63) / 64;
  const int nbW  = (N * 64 + 255) / 256;

  // ---- weight pre-transpose (bf16) ----
  k_prepB<<<16, 256, 0, stream>>>(W1, Bt1, N_FEAT, 64);
  k_prepB<<<2,  256, 0, stream>>>(W2, Bt2, N_HID, 64);

  // ---- CSR build (shared by both conv layers) ----
  hipMemsetAsync(hist, 0, (size_t)NPART * H * 8, stream);
  k_degcnt2<<<nbE, 256, 0, stream>>>(col, ew, hist, H, E);
  k_reduce <<<nbN, 256, 0, stream>>>(hist, H, cnt, dinv, N);
  k_scan1  <<<nbN, 256, 0, stream>>>(cnt, off, bsum, N);
  k_scan2  <<<1,   256, 0, stream>>>(bsum, bsum2, nbN);
  k_scan3_initcur<<<nbN, 256, 0, stream>>>(off, bsum2, hist, H, cur, N, E);
  k_fill2  <<<nbE, 256, 0, stream>>>(row, col, ew, dinv, cur, H, pairs, E);

  // ---- layer 1 ----
  k_mfma<N_FEAT, false><<<nbT, 64, 0, stream>>>(x, Bt1, bufA, N);
  k_gather<<<nbW, 256, 0, stream>>>(off, pairs, dinv, bufA, b1, bufB, N);

  // ---- layer 2 (relu fused into A-load cvt) ----
  k_mfma<N_HID, true><<<nbT, 64, 0, stream>>>(bufB, Bt2, bufA, N);
  k_gather<<<nbW, 256, 0, stream>>>(off, pairs, dinv, bufA, b2, bufB, N);

  // ---- FC heads ----
  k_fc<<<nbG, 256, 0, stream>>>(bufB, fW1, fb1, fW2, fb2, out, N);
}

// Round 7
// 227.293 us; speedup vs baseline: 1.1201x; 1.0066x over previous
//
#include <hip/hip_runtime.h>
#include <hip/hip_bf16.h>
#include <cstdint>
#include <cstddef>

#define N_FEAT 512
#define N_HID 64
#define N_CLASS 16
#define N_CLUSTER 32
#define NPART 8          // privatized histogram partitions

typedef short short8 __attribute__((ext_vector_type(8)));
typedef float floatx4 __attribute__((ext_vector_type(4)));

__device__ __forceinline__ short f2bf(float f) {
  __hip_bfloat16 h = __float2bfloat16(f);
  return *reinterpret_cast<short*>(&h);
}

// ---------------- fast zero-fill (ROCm fillBufferAligned runs at 55 GB/s) ----------------
__global__ void k_zeroH(uint4* __restrict__ p, int n16) {
  int i = blockIdx.x * 256 + threadIdx.x;
  if (i < n16) p[i] = make_uint4(0u, 0u, 0u, 0u);
}

// ---------------- packed degree/count histogram: one u64 atomic per edge ----------------
__global__ void k_degcnt2(const int* __restrict__ col, const float* __restrict__ w,
                          unsigned long long* __restrict__ hist, int H, int E) {
  int e = blockIdx.x * 256 + threadIdx.x;
  if (e >= E) return;
  int p = blockIdx.x & (NPART - 1);
  int c = col[e];
  unsigned long long fx = (unsigned long long)__float2uint_rn(w[e] * 16777216.0f);
  atomicAdd(&hist[(size_t)p * H + c], (1ull << 40) | fx);
}

// ---------------- fold partitions -> cnt, dinv ----------------
__global__ void k_reduce(const unsigned long long* __restrict__ hist, int H,
                         int* __restrict__ cnt, float* __restrict__ dinv, int n) {
  int i = blockIdx.x * 256 + threadIdx.x;
  if (i >= n) return;
  unsigned long long tot = 0;
  #pragma unroll
  for (int p = 0; p < NPART; ++p) tot += hist[(size_t)p * H + i];
  int c = (int)(tot >> 40);
  float wsum = (float)(tot & ((1ull << 40) - 1)) * 5.9604644775390625e-08f; // 2^-24
  cnt[i] = c;
  dinv[i] = rsqrtf(1.0f + wsum);
}

// ---------------- two-level exclusive scan of cnt -> off ----------------
__global__ __launch_bounds__(256) void k_scan1(const int* __restrict__ cnt,
                                               int* __restrict__ off,
                                               int* __restrict__ bsum, int n) {
  __shared__ int sh[256];
  int t = threadIdx.x;
  int i = blockIdx.x * 256 + t;
  int v = (i < n) ? cnt[i] : 0;
  sh[t] = v;
  __syncthreads();
  #pragma unroll
  for (int d = 1; d < 256; d <<= 1) {
    int x = 0;
    if (t >= d) x = sh[t - d];
    __syncthreads();
    if (t >= d) sh[t] += x;
    __syncthreads();
  }
  if (i < n) off[i] = sh[t] - v;
  if (t == 255) bsum[blockIdx.x] = sh[255];
}

__global__ __launch_bounds__(256) void k_scan2(const int* __restrict__ bsum,
                                               int* __restrict__ bsum2, int nb) {
  __shared__ int sh[256];
  int t = threadIdx.x;
  int v = (t < nb) ? bsum[t] : 0;
  sh[t] = v;
  __syncthreads();
  #pragma unroll
  for (int d = 1; d < 256; d <<= 1) {
    int x = 0;
    if (t >= d) x = sh[t - d];
    __syncthreads();
    if (t >= d) sh[t] += x;
    __syncthreads();
  }
  if (t < nb) bsum2[t] = sh[t] - v;
}

__global__ void k_scan3_initcur(int* __restrict__ off, const int* __restrict__ bsum2,
                                const unsigned long long* __restrict__ hist, int H,
                                int* __restrict__ cur, int n, int E) {
  int i = blockIdx.x * 256 + threadIdx.x;
  if (i < n) {
    int o = off[i] + bsum2[blockIdx.x];
    off[i] = o;
    int running = o;
    #pragma unroll
    for (int p = 0; p < NPART; ++p) {
      cur[(size_t)p * H + i] = running;
      running += (int)(hist[(size_t)p * H + i] >> 40);
    }
  }
  if (i == 0) off[n] = E;
}

// ---------------- fill CSR slots: single 8B (src, coef) store per edge ----------------
__global__ void k_fill2(const int* __restrict__ rowi, const int* __restrict__ coli,
                        const float* __restrict__ w, const float* __restrict__ dinv,
                        int* __restrict__ cur, int H,
                        int2* __restrict__ pairs, int E) {
  int e = blockIdx.x * 256 + threadIdx.x;
  if (e >= E) return;
  int p = blockIdx.x & (NPART - 1);       // must match k_degcnt2's mapping
  int r = rowi[e], c = coli[e];
  int pos = atomicAdd(&cur[(size_t)p * H + c], 1);
  pairs[pos] = make_int2(r, __float_as_int(dinv[r] * w[e] * dinv[c]));
}

// ---------------- W[K][64] fp32 -> Bt[64][K+8] bf16 (transposed, padded) ----------------
__global__ void k_prepB(const float* __restrict__ W, short* __restrict__ Bt,
                        int K, int ncol) {
  int idx = blockIdx.x * 256 + threadIdx.x;
  int kg = K >> 3;
  if (idx >= ncol * kg) return;
  int c = idx / kg, g = idx - c * kg;
  short8 v;
  #pragma unroll
  for (int j = 0; j < 8; ++j) v[j] = f2bf(W[(size_t)(g * 8 + j) * ncol + c]);
  *(short8*)(Bt + (size_t)c * (K + 8) + g * 8) = v;
}

// ---------------- MFMA GEMM: C[M,64] = act(A[M,K]) @ B[K,64] ----------------
// One wave per 16-row tile, no LDS/barriers. P-deep rotating register pipeline;
// sched_barrier(0) pins prefetch loads ahead of the MFMA cluster (round 6:
// without it the scheduler sank all loads to their uses -> VGPR 48, collapsed).
// __launch_bounds__(64,3): VGPR budget ~170 (3 waves/SIMD = 12/CU = grid fit).
template<int K, bool RELU>
__global__ __launch_bounds__(64, 3) void k_mfma(
    const float* __restrict__ A, const short* __restrict__ Bt,
    float* __restrict__ C, int M) {
  constexpr int BS = K + 8;
  constexpr int NSTEP = K / 32;
  constexpr int P = (NSTEP < 4) ? NSTEP : 4;
  const int lane = threadIdx.x & 63;
  const int rbase = blockIdx.x * 16;
  int r = rbase + (lane & 15);
  if (r >= M) r = M - 1;                    // only its own D-row is garbage
  const int klo = (lane >> 4) * 8;
  const float* arow = A + (size_t)r * K + klo;
  const short* bbase = Bt + (size_t)(lane & 15) * BS + klo;

  float4 pa0[P], pa1[P];
  short8 pb[P][4];
  #pragma unroll
  for (int s = 0; s < P; ++s) {
    pa0[s] = *(const float4*)(arow + s * 32);
    pa1[s] = *(const float4*)(arow + s * 32 + 4);
    #pragma unroll
    for (int j = 0; j < 4; ++j)
      pb[s][j] = *(const short8*)(bbase + (size_t)j * 16 * BS + s * 32);
  }
  __builtin_amdgcn_sched_barrier(0);        // prologue loads stay issued up-front

  floatx4 acc[4];
  #pragma unroll
  for (int j = 0; j < 4; ++j) acc[j] = (floatx4){0.f, 0.f, 0.f, 0.f};

  #pragma unroll
  for (int s = 0; s < NSTEP; ++s) {
    const int sl = s % P;                   // constant after unroll
    float4 a0 = pa0[sl], a1 = pa1[sl];
    short8 b0 = pb[sl][0], b1 = pb[sl][1], b2 = pb[sl][2], b3 = pb[sl][3];
    if (s + P < NSTEP) {                    // refill slot sl for step s+P
      pa0[sl] = *(const float4*)(arow + (s + P) * 32);
      pa1[sl] = *(const float4*)(arow + (s + P) * 32 + 4);
      #pragma unroll
      for (int j = 0; j < 4; ++j)
        pb[sl][j] = *(const short8*)(bbase + (size_t)j * 16 * BS + (s + P) * 32);
    }
    __builtin_amdgcn_sched_barrier(0);      // refill can't sink past compute
    if (RELU) {
      a0.x = fmaxf(a0.x, 0.f); a0.y = fmaxf(a0.y, 0.f);
      a0.z = fmaxf(a0.z, 0.f); a0.w = fmaxf(a0.w, 0.f);
      a1.x = fmaxf(a1.x, 0.f); a1.y = fmaxf(a1.y, 0.f);
      a1.z = fmaxf(a1.z, 0.f); a1.w = fmaxf(a1.w, 0.f);
    }
    short8 af;
    af[0] = f2bf(a0.x); af[1] = f2bf(a0.y); af[2] = f2bf(a0.z); af[3] = f2bf(a0.w);
    af[4] = f2bf(a1.x); af[5] = f2bf(a1.y); af[6] = f2bf(a1.z); af[7] = f2bf(a1.w);
    acc[0] = __builtin_amdgcn_mfma_f32_16x16x32_bf16(af, b0, acc[0], 0, 0, 0);
    acc[1] = __builtin_amdgcn_mfma_f32_16x16x32_bf16(af, b1, acc[1], 0, 0, 0);
    acc[2] = __builtin_amdgcn_mfma_f32_16x16x32_bf16(af, b2, acc[2], 0, 0, 0);
    acc[3] = __builtin_amdgcn_mfma_f32_16x16x32_bf16(af, b3, acc[3], 0, 0, 0);
  }

  const int srow = rbase + (lane >> 4) * 4;
  const int scol = lane & 15;
  #pragma unroll
  for (int i = 0; i < 4; ++i) {
    int rr = srow + i;
    if (rr < M) {
      #pragma unroll
      for (int j = 0; j < 4; ++j)
        C[(size_t)rr * 64 + j * 16 + scol] = acc[j][i];
    }
  }
}

// ---------------- gather conv: one wave per node, lane = feature dim ----------------
__global__ __launch_bounds__(256) void k_gather(
    const int* __restrict__ off, const int2* __restrict__ pairs,
    const float* __restrict__ dinv,
    const float* __restrict__ xw, const float* __restrict__ bias,
    float* __restrict__ h, int n) {
  int gid = blockIdx.x * 256 + threadIdx.x;
  int c = gid >> 6, lane = gid & 63;
  if (c >= n) return;
  float s = dinv[c]; s *= s;
  float acc = fmaf(xw[(size_t)c * 64 + lane], s, bias[lane]);
  int i = off[c], end = off[c + 1];
  for (; i + 3 < end; i += 4) {
    int2 p0 = pairs[i], p1 = pairs[i + 1], p2 = pairs[i + 2], p3 = pairs[i + 3];
    float v0 = xw[(size_t)p0.x * 64 + lane];
    float v1 = xw[(size_t)p1.x * 64 + lane];
    float v2 = xw[(size_t)p2.x * 64 + lane];
    float v3 = xw[(size_t)p3.x * 64 + lane];
    acc = fmaf(v0, __int_as_float(p0.y), acc);
    acc = fmaf(v1, __int_as_float(p1.y), acc);
    acc = fmaf(v2, __int_as_float(p2.y), acc);
    acc = fmaf(v3, __int_as_float(p3.y), acc);
  }
  for (; i < end; ++i) {
    int2 p = pairs[i];
    acc = fmaf(xw[(size_t)p.x * 64 + lane], __int_as_float(p.y), acc);
  }
  h[(size_t)c * 64 + lane] = acc;
}

// ---------------- fused FC head ----------------
__global__ __launch_bounds__(256) void k_fc(
    const float* __restrict__ h,
    const float* __restrict__ fW1, const float* __restrict__ fb1,
    const float* __restrict__ fW2, const float* __restrict__ fb2,
    float* __restrict__ out, int M) {
  __shared__ float Hs[64][68];
  __shared__ float Ws[64][48];
  __shared__ float bs[48];
  const int t = threadIdx.x;
  const int row0 = blockIdx.x * 64;
  #pragma unroll
  for (int i = 0; i < 4; ++i) {
    int f = t + i * 256;
    int r = f >> 4, k4 = f & 15;
    int rr = row0 + r;
    float4 v = make_float4(0.f, 0.f, 0.f, 0.f);
    if (rr < M) v = *(const float4*)&h[(size_t)rr * 64 + k4 * 4];
    *(float4*)&Hs[r][k4 * 4] = v;
  }
  for (int f = t; f < 64 * 48; f += 256) {
    int k = f / 48, c = f - k * 48;
    Ws[k][c] = (c < 16) ? fW1[k * 16 + c] : fW2[k * 32 + (c - 16)];
  }
  if (t < 48) bs[t] = (t < 16) ? fb1[t] : fb2[t - 16];
  __syncthreads();
  const int tr = t >> 4, tc = t & 15;
  float acc[4][3] = {{0.f}};
  #pragma unroll 8
  for (int k = 0; k < 64; ++k) {
    float a[4], b[3];
    #pragma unroll
    for (int i = 0; i < 4; ++i) a[i] = Hs[tr * 4 + i][k];
    #pragma unroll
    for (int j = 0; j < 3; ++j) b[j] = Ws[k][tc * 3 + j];
    #pragma unroll
    for (int i = 0; i < 4; ++i)
      #pragma unroll
      for (int j = 0; j < 3; ++j) acc[i][j] = fmaf(a[i], b[j], acc[i][j]);
  }
  #pragma unroll
  for (int i = 0; i < 4; ++i) {
    int rr = row0 + tr * 4 + i;
    if (rr >= M) continue;
    #pragma unroll
    for (int j = 0; j < 3; ++j) {
      int c = tc * 3 + j;
      float v = acc[i][j] + bs[c];
      if (c < 16) out[(size_t)rr * 16 + c] = v;
      else out[(size_t)M * 16 + (size_t)rr * 32 + (c - 16)] = v;
    }
  }
}

extern "C" void kernel_launch(void* const* d_in, const int* in_sizes, int n_in,
                              void* d_out, int out_size, void* d_ws, size_t ws_size,
                              hipStream_t stream) {
  const float* x    = (const float*)d_in[0];
  const int*   ei   = (const int*)d_in[1];
  const float* ew   = (const float*)d_in[2];
  const float* W1   = (const float*)d_in[3];
  const float* b1   = (const float*)d_in[4];
  const float* W2   = (const float*)d_in[5];
  const float* b2   = (const float*)d_in[6];
  const float* fW1  = (const float*)d_in[7];
  const float* fb1  = (const float*)d_in[8];
  const float* fW2  = (const float*)d_in[9];
  const float* fb2  = (const float*)d_in[10];
  float* out = (float*)d_out;

  const int N = in_sizes[0] / N_FEAT;
  const int E = in_sizes[2];
  const int H = (N + 63) & ~63;
  const int* row = ei;
  const int* col = ei + E;

  char* ws = (char*)d_ws;
  float*              dinv = (float*)(ws + 0x000000);              // N f
  int*                cnt  = (int*)  (ws + 0x040000);              // N i
  int*                off  = (int*)  (ws + 0x080000);              // N+1 i
  int*                bsum = (int*)  (ws + 0x0C0000);
  int*                bsum2= (int*)  (ws + 0x0C1000);
  short*              Bt1  = (short*)(ws + 0x0C8000);              // 64*520 bf16
  short*              Bt2  = (short*)(ws + 0x0DA000);              // 64*72 bf16
  unsigned long long* hist = (unsigned long long*)(ws + 0x100000); // 8*H u64 (3.2MB)
  int*                cur  = (int*)  (ws + 0x500000);              // 8*H i (1.6MB)
  int2*               pairs= (int2*) (ws + 0x6C0000);              // E int2 (6.4MB)
  float*              bufA = (float*)(ws + 0xD40000);              // N*64 f (12.8MB)
  float*              bufB = (float*)(ws + 0x1980000);             // N*64 f (12.8MB)

  const int nbN  = (N + 255) / 256;
  const int nbE  = (E + 255) / 256;
  const int nbT  = (N + 15) / 16;          // one wave (16 rows) per block
  const int nbG  = (N + 63) / 64;
  const int nbW  = (N * 64 + 255) / 256;
  const int nH16 = NPART * H / 2;          // hist size in uint4 units
  const int nbZ  = (nH16 + 255) / 256;

  // ---- weight pre-transpose (bf16) ----
  k_prepB<<<16, 256, 0, stream>>>(W1, Bt1, N_FEAT, 64);
  k_prepB<<<2,  256, 0, stream>>>(W2, Bt2, N_HID, 64);

  // ---- CSR build (shared by both conv layers) ----
  k_zeroH  <<<nbZ, 256, 0, stream>>>((uint4*)hist, nH16);
  k_degcnt2<<<nbE, 256, 0, stream>>>(col, ew, hist, H, E);
  k_reduce <<<nbN, 256, 0, stream>>>(hist, H, cnt, dinv, N);
  k_scan1  <<<nbN, 256, 0, stream>>>(cnt, off, bsum, N);
  k_scan2  <<<1,   256, 0, stream>>>(bsum, bsum2, nbN);
  k_scan3_initcur<<<nbN, 256, 0, stream>>>(off, bsum2, hist, H, cur, N, E);
  k_fill2  <<<nbE, 256, 0, stream>>>(row, col, ew, dinv, cur, H, pairs, E);

  // ---- layer 1 ----
  k_mfma<N_FEAT, false><<<nbT, 64, 0, stream>>>(x, Bt1, bufA, N);
  k_gather<<<nbW, 256, 0, stream>>>(off, pairs, dinv, bufA, b1, bufB, N);

  // ---- layer 2 (relu fused into A-load cvt) ----
  k_mfma<N_HID, true><<<nbT, 64, 0, stream>>>(bufB, Bt2, bufA, N);
  k_gather<<<nbW, 256, 0, stream>>>(off, pairs, dinv, bufA, b2, bufB, N);

  // ---- FC heads ----
  k_fc<<<nbG, 256, 0, stream>>>(bufB, fW1, fb1, fW2, fb2, out, N);
}

// Round 8
// 212.210 us; speedup vs baseline: 1.1997x; 1.0711x over previous
//
#include <hip/hip_runtime.h>
#include <hip/hip_bf16.h>
#include <cstdint>
#include <cstddef>

#define N_FEAT 512
#define N_HID 64
#define N_CLASS 16
#define N_CLUSTER 32
#define NPART 8          // privatized histogram partitions

typedef short short8 __attribute__((ext_vector_type(8)));
typedef float floatx4 __attribute__((ext_vector_type(4)));

__device__ __forceinline__ short f2bf(float f) {
  __hip_bfloat16 h = __float2bfloat16(f);
  return *reinterpret_cast<short*>(&h);
}

// ---------------- fast zero-fill ----------------
__global__ void k_zeroH(uint4* __restrict__ p, int n16) {
  int i = blockIdx.x * 256 + threadIdx.x;
  if (i < n16) p[i] = make_uint4(0u, 0u, 0u, 0u);
}

// ---------------- packed degree/count histogram: one u64 atomic per edge ----------------
__global__ void k_degcnt2(const int* __restrict__ col, const float* __restrict__ w,
                          unsigned long long* __restrict__ hist, int H, int E) {
  int e = blockIdx.x * 256 + threadIdx.x;
  if (e >= E) return;
  int p = blockIdx.x & (NPART - 1);
  int c = col[e];
  unsigned long long fx = (unsigned long long)__float2uint_rn(w[e] * 16777216.0f);
  atomicAdd(&hist[(size_t)p * H + c], (1ull << 40) | fx);
}

// ---------------- fold partitions -> cnt, dinv ----------------
__global__ void k_reduce(const unsigned long long* __restrict__ hist, int H,
                         int* __restrict__ cnt, float* __restrict__ dinv, int n) {
  int i = blockIdx.x * 256 + threadIdx.x;
  if (i >= n) return;
  unsigned long long tot = 0;
  #pragma unroll
  for (int p = 0; p < NPART; ++p) tot += hist[(size_t)p * H + i];
  int c = (int)(tot >> 40);
  float wsum = (float)(tot & ((1ull << 40) - 1)) * 5.9604644775390625e-08f; // 2^-24
  cnt[i] = c;
  dinv[i] = rsqrtf(1.0f + wsum);
}

// ---------------- two-level exclusive scan of cnt -> off ----------------
__global__ __launch_bounds__(256) void k_scan1(const int* __restrict__ cnt,
                                               int* __restrict__ off,
                                               int* __restrict__ bsum, int n) {
  __shared__ int sh[256];
  int t = threadIdx.x;
  int i = blockIdx.x * 256 + t;
  int v = (i < n) ? cnt[i] : 0;
  sh[t] = v;
  __syncthreads();
  #pragma unroll
  for (int d = 1; d < 256; d <<= 1) {
    int x = 0;
    if (t >= d) x = sh[t - d];
    __syncthreads();
    if (t >= d) sh[t] += x;
    __syncthreads();
  }
  if (i < n) off[i] = sh[t] - v;
  if (t == 255) bsum[blockIdx.x] = sh[255];
}

__global__ __launch_bounds__(256) void k_scan2(const int* __restrict__ bsum,
                                               int* __restrict__ bsum2, int nb) {
  __shared__ int sh[256];
  int t = threadIdx.x;
  int v = (t < nb) ? bsum[t] : 0;
  sh[t] = v;
  __syncthreads();
  #pragma unroll
  for (int d = 1; d < 256; d <<= 1) {
    int x = 0;
    if (t >= d) x = sh[t - d];
    __syncthreads();
    if (t >= d) sh[t] += x;
    __syncthreads();
  }
  if (t < nb) bsum2[t] = sh[t] - v;
}

__global__ void k_scan3_initcur(int* __restrict__ off, const int* __restrict__ bsum2,
                                const unsigned long long* __restrict__ hist, int H,
                                int* __restrict__ cur, int n, int E) {
  int i = blockIdx.x * 256 + threadIdx.x;
  if (i < n) {
    int o = off[i] + bsum2[blockIdx.x];
    off[i] = o;
    int running = o;
    #pragma unroll
    for (int p = 0; p < NPART; ++p) {
      cur[(size_t)p * H + i] = running;
      running += (int)(hist[(size_t)p * H + i] >> 40);
    }
  }
  if (i == 0) off[n] = E;
}

// ---------------- fill CSR slots: single 8B (src, coef) store per edge ----------------
__global__ void k_fill2(const int* __restrict__ rowi, const int* __restrict__ coli,
                        const float* __restrict__ w, const float* __restrict__ dinv,
                        int* __restrict__ cur, int H,
                        int2* __restrict__ pairs, int E) {
  int e = blockIdx.x * 256 + threadIdx.x;
  if (e >= E) return;
  int p = blockIdx.x & (NPART - 1);       // must match k_degcnt2's mapping
  int r = rowi[e], c = coli[e];
  int pos = atomicAdd(&cur[(size_t)p * H + c], 1);
  pairs[pos] = make_int2(r, __float_as_int(dinv[r] * w[e] * dinv[c]));
}

// ---------------- W[K][64] fp32 -> BF in MFMA-fragment order (bf16) ----------------
// BF granule idx = (s*4 + j)*64 + lane holds W[k0..k0+7][col] where
// col = j*16 + (lane&15), k0 = s*32 + (lane>>4)*8.  A wave's B-load for
// (s,j) is then a fully CONTIGUOUS 1KB read (round 6/7: 16-way fractured).
__global__ void k_prepBF(const float* __restrict__ W, short* __restrict__ BF, int K) {
  int idx = blockIdx.x * 256 + threadIdx.x;
  int total = (K / 32) * 4 * 64;
  if (idx >= total) return;
  int lane = idx & 63;
  int sj = idx >> 6;
  int j = sj & 3, s = sj >> 2;
  int col = j * 16 + (lane & 15);
  int k0 = s * 32 + ((lane >> 4) << 3);
  short8 v;
  #pragma unroll
  for (int t = 0; t < 8; ++t) v[t] = f2bf(W[(size_t)(k0 + t) * 64 + col]);
  *(short8*)(BF + (size_t)idx * 8) = v;
}

// ---------------- MFMA GEMM: C[M,64] = act(A[M,K]) @ B[K,64] ----------------
// One wave per 16-row tile, no LDS. B fragments contiguous/L1-hot from BF.
// A: PA-deep rotating register pipeline; consume-then-refill keeps VGPR ~100
// -> __launch_bounds__(64,4) (cap 128) for 16 waves/CU.
template<int K, bool RELU>
__global__ __launch_bounds__(64, 4) void k_mfma(
    const float* __restrict__ A, const short8* __restrict__ BF,
    float* __restrict__ C, int M) {
  constexpr int NSTEP = K / 32;
  constexpr int PA = (NSTEP < 4) ? NSTEP : 4;
  constexpr int PB = (NSTEP < 2) ? NSTEP : 2;
  const int lane = threadIdx.x & 63;
  const int rbase = blockIdx.x * 16;
  int r = rbase + (lane & 15);
  if (r >= M) r = M - 1;                    // only its own D-row is garbage
  const int klo = (lane >> 4) * 8;
  const float* arow = A + (size_t)r * K + klo;
  const short8* bbase = BF + lane;

  float4 pa0[PA], pa1[PA];
  short8 pb[PB][4];
  #pragma unroll
  for (int s = 0; s < PA; ++s) {
    pa0[s] = *(const float4*)(arow + s * 32);
    pa1[s] = *(const float4*)(arow + s * 32 + 4);
  }
  #pragma unroll
  for (int s = 0; s < PB; ++s) {
    #pragma unroll
    for (int j = 0; j < 4; ++j)
      pb[s][j] = bbase[(s * 4 + j) * 64];
  }
  __builtin_amdgcn_sched_barrier(0);        // prologue loads stay up-front

  floatx4 acc[4];
  #pragma unroll
  for (int j = 0; j < 4; ++j) acc[j] = (floatx4){0.f, 0.f, 0.f, 0.f};

  #pragma unroll
  for (int s = 0; s < NSTEP; ++s) {
    const int sa = s % PA;                  // constant after unroll
    const int sb = s % PB;
    // ---- consume slot: cvt + 4 MFMA ----
    float4 a0 = pa0[sa], a1 = pa1[sa];
    if (RELU) {
      a0.x = fmaxf(a0.x, 0.f); a0.y = fmaxf(a0.y, 0.f);
      a0.z = fmaxf(a0.z, 0.f); a0.w = fmaxf(a0.w, 0.f);
      a1.x = fmaxf(a1.x, 0.f); a1.y = fmaxf(a1.y, 0.f);
      a1.z = fmaxf(a1.z, 0.f); a1.w = fmaxf(a1.w, 0.f);
    }
    short8 af;
    af[0] = f2bf(a0.x); af[1] = f2bf(a0.y); af[2] = f2bf(a0.z); af[3] = f2bf(a0.w);
    af[4] = f2bf(a1.x); af[5] = f2bf(a1.y); af[6] = f2bf(a1.z); af[7] = f2bf(a1.w);
    acc[0] = __builtin_amdgcn_mfma_f32_16x16x32_bf16(af, pb[sb][0], acc[0], 0, 0, 0);
    acc[1] = __builtin_amdgcn_mfma_f32_16x16x32_bf16(af, pb[sb][1], acc[1], 0, 0, 0);
    acc[2] = __builtin_amdgcn_mfma_f32_16x16x32_bf16(af, pb[sb][2], acc[2], 0, 0, 0);
    acc[3] = __builtin_amdgcn_mfma_f32_16x16x32_bf16(af, pb[sb][3], acc[3], 0, 0, 0);
    // ---- refill slot for step s+P ----
    if (s + PA < NSTEP) {
      pa0[sa] = *(const float4*)(arow + (s + PA) * 32);
      pa1[sa] = *(const float4*)(arow + (s + PA) * 32 + 4);
    }
    if (s + PB < NSTEP) {
      #pragma unroll
      for (int j = 0; j < 4; ++j)
        pb[sb][j] = bbase[((s + PB) * 4 + j) * 64];
    }
    __builtin_amdgcn_sched_barrier(0);      // refills can't sink past next MFMAs
  }

  const int srow = rbase + (lane >> 4) * 4;
  const int scol = lane & 15;
  #pragma unroll
  for (int i = 0; i < 4; ++i) {
    int rr = srow + i;
    if (rr < M) {
      #pragma unroll
      for (int j = 0; j < 4; ++j)
        C[(size_t)rr * 64 + j * 16 + scol] = acc[j][i];
    }
  }
}

// ---------------- gather conv: one wave per node, lane = feature dim ----------------
__global__ __launch_bounds__(256) void k_gather(
    const int* __restrict__ off, const int2* __restrict__ pairs,
    const float* __restrict__ dinv,
    const float* __restrict__ xw, const float* __restrict__ bias,
    float* __restrict__ h, int n) {
  int gid = blockIdx.x * 256 + threadIdx.x;
  int c = gid >> 6, lane = gid & 63;
  if (c >= n) return;
  float s = dinv[c]; s *= s;
  float acc = fmaf(xw[(size_t)c * 64 + lane], s, bias[lane]);
  int i = off[c], end = off[c + 1];
  for (; i + 7 < end; i += 8) {             // 8-deep MLP on the 2-level chain
    int2 p[8];
    float v[8];
    #pragma unroll
    for (int t = 0; t < 8; ++t) p[t] = pairs[i + t];
    #pragma unroll
    for (int t = 0; t < 8; ++t) v[t] = xw[(size_t)p[t].x * 64 + lane];
    #pragma unroll
    for (int t = 0; t < 8; ++t) acc = fmaf(v[t], __int_as_float(p[t].y), acc);
  }
  for (; i + 1 < end; i += 2) {
    int2 p0 = pairs[i], p1 = pairs[i + 1];
    float v0 = xw[(size_t)p0.x * 64 + lane];
    float v1 = xw[(size_t)p1.x * 64 + lane];
    acc = fmaf(v0, __int_as_float(p0.y), acc);
    acc = fmaf(v1, __int_as_float(p1.y), acc);
  }
  if (i < end) {
    int2 p = pairs[i];
    acc = fmaf(xw[(size_t)p.x * 64 + lane], __int_as_float(p.y), acc);
  }
  h[(size_t)c * 64 + lane] = acc;
}

// ---------------- fused FC head ----------------
__global__ __launch_bounds__(256) void k_fc(
    const float* __restrict__ h,
    const float* __restrict__ fW1, const float* __restrict__ fb1,
    const float* __restrict__ fW2, const float* __restrict__ fb2,
    float* __restrict__ out, int M) {
  __shared__ float Hs[64][68];
  __shared__ float Ws[64][48];
  __shared__ float bs[48];
  const int t = threadIdx.x;
  const int row0 = blockIdx.x * 64;
  #pragma unroll
  for (int i = 0; i < 4; ++i) {
    int f = t + i * 256;
    int r = f >> 4, k4 = f & 15;
    int rr = row0 + r;
    float4 v = make_float4(0.f, 0.f, 0.f, 0.f);
    if (rr < M) v = *(const float4*)&h[(size_t)rr * 64 + k4 * 4];
    *(float4*)&Hs[r][k4 * 4] = v;
  }
  for (int f = t; f < 64 * 48; f += 256) {
    int k = f / 48, c = f - k * 48;
    Ws[k][c] = (c < 16) ? fW1[k * 16 + c] : fW2[k * 32 + (c - 16)];
  }
  if (t < 48) bs[t] = (t < 16) ? fb1[t] : fb2[t - 16];
  __syncthreads();
  const int tr = t >> 4, tc = t & 15;
  float acc[4][3] = {{0.f}};
  #pragma unroll 8
  for (int k = 0; k < 64; ++k) {
    float a[4], b[3];
    #pragma unroll
    for (int i = 0; i < 4; ++i) a[i] = Hs[tr * 4 + i][k];
    #pragma unroll
    for (int j = 0; j < 3; ++j) b[j] = Ws[k][tc * 3 + j];
    #pragma unroll
    for (int i = 0; i < 4; ++i)
      #pragma unroll
      for (int j = 0; j < 3; ++j) acc[i][j] = fmaf(a[i], b[j], acc[i][j]);
  }
  #pragma unroll
  for (int i = 0; i < 4; ++i) {
    int rr = row0 + tr * 4 + i;
    if (rr >= M) continue;
    #pragma unroll
    for (int j = 0; j < 3; ++j) {
      int c = tc * 3 + j;
      float v = acc[i][j] + bs[c];
      if (c < 16) out[(size_t)rr * 16 + c] = v;
      else out[(size_t)M * 16 + (size_t)rr * 32 + (c - 16)] = v;
    }
  }
}

extern "C" void kernel_launch(void* const* d_in, const int* in_sizes, int n_in,
                              void* d_out, int out_size, void* d_ws, size_t ws_size,
                              hipStream_t stream) {
  const float* x    = (const float*)d_in[0];
  const int*   ei   = (const int*)d_in[1];
  const float* ew   = (const float*)d_in[2];
  const float* W1   = (const float*)d_in[3];
  const float* b1   = (const float*)d_in[4];
  const float* W2   = (const float*)d_in[5];
  const float* b2   = (const float*)d_in[6];
  const float* fW1  = (const float*)d_in[7];
  const float* fb1  = (const float*)d_in[8];
  const float* fW2  = (const float*)d_in[9];
  const float* fb2  = (const float*)d_in[10];
  float* out = (float*)d_out;

  const int N = in_sizes[0] / N_FEAT;
  const int E = in_sizes[2];
  const int H = (N + 63) & ~63;
  const int* row = ei;
  const int* col = ei + E;

  char* ws = (char*)d_ws;
  float*              dinv = (float*)(ws + 0x000000);              // N f
  int*                cnt  = (int*)  (ws + 0x040000);              // N i
  int*                off  = (int*)  (ws + 0x080000);              // N+1 i
  int*                bsum = (int*)  (ws + 0x0C0000);
  int*                bsum2= (int*)  (ws + 0x0C1000);
  short*              BF1  = (short*)(ws + 0x0C8000);              // 64KB frag-order B1
  short*              BF2  = (short*)(ws + 0x0DA000);              // 8KB frag-order B2
  unsigned long long* hist = (unsigned long long*)(ws + 0x100000); // 8*H u64 (3.2MB)
  int*                cur  = (int*)  (ws + 0x500000);              // 8*H i (1.6MB)
  int2*               pairs= (int2*) (ws + 0x6C0000);              // E int2 (6.4MB)
  float*              bufA = (float*)(ws + 0xD40000);              // N*64 f (12.8MB)
  float*              bufB = (float*)(ws + 0x1980000);             // N*64 f (12.8MB)

  const int nbN  = (N + 255) / 256;
  const int nbE  = (E + 255) / 256;
  const int nbT  = (N + 15) / 16;          // one wave (16 rows) per block
  const int nbG  = (N + 63) / 64;
  const int nbW  = (N * 64 + 255) / 256;
  const int nH16 = NPART * H / 2;          // hist size in uint4 units
  const int nbZ  = (nH16 + 255) / 256;

  // ---- weight pre-pack into MFMA fragment order (bf16) ----
  k_prepBF<<<32, 256, 0, stream>>>(W1, BF1, N_FEAT);
  k_prepBF<<<2,  256, 0, stream>>>(W2, BF2, N_HID);

  // ---- CSR build (shared by both conv layers) ----
  k_zeroH  <<<nbZ, 256, 0, stream>>>((uint4*)hist, nH16);
  k_degcnt2<<<nbE, 256, 0, stream>>>(col, ew, hist, H, E);
  k_reduce <<<nbN, 256, 0, stream>>>(hist, H, cnt, dinv, N);
  k_scan1  <<<nbN, 256, 0, stream>>>(cnt, off, bsum, N);
  k_scan2  <<<1,   256, 0, stream>>>(bsum, bsum2, nbN);
  k_scan3_initcur<<<nbN, 256, 0, stream>>>(off, bsum2, hist, H, cur, N, E);
  k_fill2  <<<nbE, 256, 0, stream>>>(row, col, ew, dinv, cur, H, pairs, E);

  // ---- layer 1 ----
  k_mfma<N_FEAT, false><<<nbT, 64, 0, stream>>>(x, (const short8*)BF1, bufA, N);
  k_gather<<<nbW, 256, 0, stream>>>(off, pairs, dinv, bufA, b1, bufB, N);

  // ---- layer 2 (relu fused into A-load cvt) ----
  k_mfma<N_HID, true><<<nbT, 64, 0, stream>>>(bufB, (const short8*)BF2, bufA, N);
  k_gather<<<nbW, 256, 0, stream>>>(off, pairs, dinv, bufA, b2, bufB, N);

  // ---- FC heads ----
  k_fc<<<nbG, 256, 0, stream>>>(bufB, fW1, fb1, fW2, fb2, out, N);
}

// Round 9
// 196.569 us; speedup vs baseline: 1.2952x; 1.0796x over previous
//
#include <hip/hip_runtime.h>
#include <hip/hip_bf16.h>
#include <cstdint>
#include <cstddef>

#define N_FEAT 512
#define N_HID 64
#define N_CLASS 16
#define N_CLUSTER 32
#define NPART 8          // privatized histogram partitions

typedef short short8 __attribute__((ext_vector_type(8)));
typedef float floatx4 __attribute__((ext_vector_type(4)));
typedef unsigned short u16;
typedef unsigned short u16x4 __attribute__((ext_vector_type(4)));

__device__ __forceinline__ short f2bf(float f) {
  __hip_bfloat16 h = __float2bfloat16(f);   // RNE
  return *reinterpret_cast<short*>(&h);
}
__device__ __forceinline__ u16 f2bfu(float f) { return (u16)f2bf(f); }
__device__ __forceinline__ float bf2f(u16 u) {
  return __uint_as_float((unsigned)u << 16);
}

// ---------------- fast zero-fill ----------------
__global__ void k_zeroH(uint4* __restrict__ p, int n16) {
  int i = blockIdx.x * 256 + threadIdx.x;
  if (i < n16) p[i] = make_uint4(0u, 0u, 0u, 0u);
}

// ---------------- packed degree/count histogram: one u64 atomic per edge ----------------
__global__ void k_degcnt2(const int* __restrict__ col, const float* __restrict__ w,
                          unsigned long long* __restrict__ hist, int H, int E) {
  int e = blockIdx.x * 256 + threadIdx.x;
  if (e >= E) return;
  int p = blockIdx.x & (NPART - 1);
  int c = col[e];
  unsigned long long fx = (unsigned long long)__float2uint_rn(w[e] * 16777216.0f);
  atomicAdd(&hist[(size_t)p * H + c], (1ull << 40) | fx);
}

// ---------------- fold partitions -> cnt, dinv ----------------
__global__ void k_reduce(const unsigned long long* __restrict__ hist, int H,
                         int* __restrict__ cnt, float* __restrict__ dinv, int n) {
  int i = blockIdx.x * 256 + threadIdx.x;
  if (i >= n) return;
  unsigned long long tot = 0;
  #pragma unroll
  for (int p = 0; p < NPART; ++p) tot += hist[(size_t)p * H + i];
  int c = (int)(tot >> 40);
  float wsum = (float)(tot & ((1ull << 40) - 1)) * 5.9604644775390625e-08f; // 2^-24
  cnt[i] = c;
  dinv[i] = rsqrtf(1.0f + wsum);
}

// ---------------- two-level exclusive scan of cnt -> off ----------------
__global__ __launch_bounds__(256) void k_scan1(const int* __restrict__ cnt,
                                               int* __restrict__ off,
                                               int* __restrict__ bsum, int n) {
  __shared__ int sh[256];
  int t = threadIdx.x;
  int i = blockIdx.x * 256 + t;
  int v = (i < n) ? cnt[i] : 0;
  sh[t] = v;
  __syncthreads();
  #pragma unroll
  for (int d = 1; d < 256; d <<= 1) {
    int x = 0;
    if (t >= d) x = sh[t - d];
    __syncthreads();
    if (t >= d) sh[t] += x;
    __syncthreads();
  }
  if (i < n) off[i] = sh[t] - v;
  if (t == 255) bsum[blockIdx.x] = sh[255];
}

__global__ __launch_bounds__(256) void k_scan2(const int* __restrict__ bsum,
                                               int* __restrict__ bsum2, int nb) {
  __shared__ int sh[256];
  int t = threadIdx.x;
  int v = (t < nb) ? bsum[t] : 0;
  sh[t] = v;
  __syncthreads();
  #pragma unroll
  for (int d = 1; d < 256; d <<= 1) {
    int x = 0;
    if (t >= d) x = sh[t - d];
    __syncthreads();
    if (t >= d) sh[t] += x;
    __syncthreads();
  }
  if (t < nb) bsum2[t] = sh[t] - v;
}

__global__ void k_scan3_initcur(int* __restrict__ off, const int* __restrict__ bsum2,
                                const unsigned long long* __restrict__ hist, int H,
                                int* __restrict__ cur, int n, int E) {
  int i = blockIdx.x * 256 + threadIdx.x;
  if (i < n) {
    int o = off[i] + bsum2[blockIdx.x];
    off[i] = o;
    int running = o;
    #pragma unroll
    for (int p = 0; p < NPART; ++p) {
      cur[(size_t)p * H + i] = running;
      running += (int)(hist[(size_t)p * H + i] >> 40);
    }
  }
  if (i == 0) off[n] = E;
}

// ---------------- fill CSR slots: ONE 4B (src16 | coef-bf16) store per edge ----------------
// N < 65536 so src fits 16 bits; coef rounded to bf16 (rel ~0.4%, within tolerance).
__global__ void k_fill2(const int* __restrict__ rowi, const int* __restrict__ coli,
                        const float* __restrict__ w, const float* __restrict__ dinv,
                        int* __restrict__ cur, int H,
                        unsigned* __restrict__ pairs, int E) {
  int e = blockIdx.x * 256 + threadIdx.x;
  if (e >= E) return;
  int p = blockIdx.x & (NPART - 1);       // must match k_degcnt2's mapping
  int r = rowi[e], c = coli[e];
  int pos = atomicAdd(&cur[(size_t)p * H + c], 1);
  unsigned pk = ((unsigned)r << 16) | (u16)f2bf(dinv[r] * w[e] * dinv[c]);
  pairs[pos] = pk;
}

// ---------------- W[K][64] fp32 -> BF in MFMA-fragment order (bf16) ----------------
// Granule idx = (s*4 + j)*64 + lane holds W[k0..k0+7][col], col = j*16+(lane&15),
// k0 = s*32+(lane>>4)*8: a wave's B-load for (s,j) is a contiguous 1KB read.
__global__ void k_prepBF(const float* __restrict__ W, short* __restrict__ BF, int K) {
  int idx = blockIdx.x * 256 + threadIdx.x;
  int total = (K / 32) * 4 * 64;
  if (idx >= total) return;
  int lane = idx & 63;
  int sj = idx >> 6;
  int j = sj & 3, s = sj >> 2;
  int col = j * 16 + (lane & 15);
  int k0 = s * 32 + ((lane >> 4) << 3);
  short8 v;
  #pragma unroll
  for (int t = 0; t < 8; ++t) v[t] = f2bf(W[(size_t)(k0 + t) * 64 + col]);
  *(short8*)(BF + (size_t)idx * 8) = v;
}

// ---------------- MFMA GEMM: C[M,64](bf16) = A[M,K] @ B[K,64] ----------------
// One wave per 16-row tile, no LDS. B frags contiguous from BF (L1/L2-hot).
// ABF=false: A fp32 (layer1, x), rotating PA-deep pipeline + cvt.
// ABF=true:  A bf16 (layer2, relu'd h1) -> direct short8 loads, no cvt.
template<int K, bool ABF>
__global__ __launch_bounds__(64, 4) void k_mfma(
    const void* __restrict__ Av, const short8* __restrict__ BF,
    u16* __restrict__ C, int M) {
  constexpr int NSTEP = K / 32;
  constexpr int PA = (NSTEP < 4) ? NSTEP : 4;
  constexpr int PB = (NSTEP < 2) ? NSTEP : 2;
  const int lane = threadIdx.x & 63;
  const int rbase = blockIdx.x * 16;
  int r = rbase + (lane & 15);
  if (r >= M) r = M - 1;                    // only its own D-row is garbage
  const int klo = (lane >> 4) * 8;
  const float* arowf = (const float*)Av + (size_t)r * K + klo;
  const u16*   arowh = (const u16*)Av + (size_t)r * K + klo;
  const short8* bbase = BF + lane;

  float4 pa0[PA], pa1[PA];
  short8 pah[PA];
  short8 pb[PB][4];
  #pragma unroll
  for (int s = 0; s < PA; ++s) {
    if constexpr (ABF) {
      pah[s] = *(const short8*)(arowh + s * 32);
    } else {
      pa0[s] = *(const float4*)(arowf + s * 32);
      pa1[s] = *(const float4*)(arowf + s * 32 + 4);
    }
  }
  #pragma unroll
  for (int s = 0; s < PB; ++s) {
    #pragma unroll
    for (int j = 0; j < 4; ++j)
      pb[s][j] = bbase[(s * 4 + j) * 64];
  }
  __builtin_amdgcn_sched_barrier(0);        // prologue loads stay up-front

  floatx4 acc[4];
  #pragma unroll
  for (int j = 0; j < 4; ++j) acc[j] = (floatx4){0.f, 0.f, 0.f, 0.f};

  #pragma unroll
  for (int s = 0; s < NSTEP; ++s) {
    const int sa = s % PA;                  // constant after unroll
    const int sb = s % PB;
    short8 af;
    if constexpr (ABF) {
      af = pah[sa];
    } else {
      float4 a0 = pa0[sa], a1 = pa1[sa];
      af[0] = f2bf(a0.x); af[1] = f2bf(a0.y); af[2] = f2bf(a0.z); af[3] = f2bf(a0.w);
      af[4] = f2bf(a1.x); af[5] = f2bf(a1.y); af[6] = f2bf(a1.z); af[7] = f2bf(a1.w);
    }
    acc[0] = __builtin_amdgcn_mfma_f32_16x16x32_bf16(af, pb[sb][0], acc[0], 0, 0, 0);
    acc[1] = __builtin_amdgcn_mfma_f32_16x16x32_bf16(af, pb[sb][1], acc[1], 0, 0, 0);
    acc[2] = __builtin_amdgcn_mfma_f32_16x16x32_bf16(af, pb[sb][2], acc[2], 0, 0, 0);
    acc[3] = __builtin_amdgcn_mfma_f32_16x16x32_bf16(af, pb[sb][3], acc[3], 0, 0, 0);
    if (s + PA < NSTEP) {                   // refill A slot
      if constexpr (ABF) {
        pah[sa] = *(const short8*)(arowh + (s + PA) * 32);
      } else {
        pa0[sa] = *(const float4*)(arowf + (s + PA) * 32);
        pa1[sa] = *(const float4*)(arowf + (s + PA) * 32 + 4);
      }
    }
    if (s + PB < NSTEP) {                   // refill B slot
      #pragma unroll
      for (int j = 0; j < 4; ++j)
        pb[sb][j] = bbase[((s + PB) * 4 + j) * 64];
    }
    __builtin_amdgcn_sched_barrier(0);      // refills can't sink past next MFMAs
  }

  const int srow = rbase + (lane >> 4) * 4;
  const int scol = lane & 15;
  #pragma unroll
  for (int i = 0; i < 4; ++i) {
    int rr = srow + i;
    if (rr < M) {
      #pragma unroll
      for (int j = 0; j < 4; ++j)
        C[(size_t)rr * 64 + j * 16 + scol] = f2bfu(acc[j][i]);
    }
  }
}

// ---------------- gather conv: one wave per node, lane = feature dim ----------------
// h[c] = (relu?) bias + dinv[c]^2*xw[c] + sum_i coef_i * xw[src_i]   (bf16 in/out)
template<bool RELU>
__global__ __launch_bounds__(256) void k_gather(
    const int* __restrict__ off, const unsigned* __restrict__ pairs,
    const float* __restrict__ dinv,
    const u16* __restrict__ xw, const float* __restrict__ bias,
    u16* __restrict__ h, int n) {
  int gid = blockIdx.x * 256 + threadIdx.x;
  int c = gid >> 6, lane = gid & 63;
  if (c >= n) return;
  float s = dinv[c]; s *= s;
  float acc = fmaf(bf2f(xw[(size_t)c * 64 + lane]), s, bias[lane]);
  int i = off[c], end = off[c + 1];
  for (; i + 7 < end; i += 8) {             // 8-deep MLP on the 2-level chain
    unsigned p[8];
    float v[8];
    #pragma unroll
    for (int t = 0; t < 8; ++t) p[t] = pairs[i + t];
    #pragma unroll
    for (int t = 0; t < 8; ++t)
      v[t] = bf2f(xw[(size_t)(p[t] >> 16) * 64 + lane]);
    #pragma unroll
    for (int t = 0; t < 8; ++t)
      acc = fmaf(v[t], __uint_as_float((p[t] & 0xffffu) << 16), acc);
  }
  for (; i + 1 < end; i += 2) {
    unsigned p0 = pairs[i], p1 = pairs[i + 1];
    float v0 = bf2f(xw[(size_t)(p0 >> 16) * 64 + lane]);
    float v1 = bf2f(xw[(size_t)(p1 >> 16) * 64 + lane]);
    acc = fmaf(v0, __uint_as_float((p0 & 0xffffu) << 16), acc);
    acc = fmaf(v1, __uint_as_float((p1 & 0xffffu) << 16), acc);
  }
  if (i < end) {
    unsigned p = pairs[i];
    acc = fmaf(bf2f(xw[(size_t)(p >> 16) * 64 + lane]),
               __uint_as_float((p & 0xffffu) << 16), acc);
  }
  if (RELU) acc = fmaxf(acc, 0.f);          // relu BEFORE rounding == ref relu then bf16
  h[(size_t)c * 64 + lane] = f2bfu(acc);
}

// ---------------- fused FC head (h in bf16) ----------------
__global__ __launch_bounds__(256) void k_fc(
    const u16* __restrict__ h,
    const float* __restrict__ fW1, const float* __restrict__ fb1,
    const float* __restrict__ fW2, const float* __restrict__ fb2,
    float* __restrict__ out, int M) {
  __shared__ float Hs[64][68];
  __shared__ float Ws[64][48];
  __shared__ float bs[48];
  const int t = threadIdx.x;
  const int row0 = blockIdx.x * 64;
  #pragma unroll
  for (int i = 0; i < 4; ++i) {
    int f = t + i * 256;
    int r = f >> 4, k4 = f & 15;
    int rr = row0 + r;
    float4 v = make_float4(0.f, 0.f, 0.f, 0.f);
    if (rr < M) {
      u16x4 u = *(const u16x4*)&h[(size_t)rr * 64 + k4 * 4];
      v = make_float4(bf2f(u[0]), bf2f(u[1]), bf2f(u[2]), bf2f(u[3]));
    }
    *(float4*)&Hs[r][k4 * 4] = v;
  }
  for (int f = t; f < 64 * 48; f += 256) {
    int k = f / 48, c = f - k * 48;
    Ws[k][c] = (c < 16) ? fW1[k * 16 + c] : fW2[k * 32 + (c - 16)];
  }
  if (t < 48) bs[t] = (t < 16) ? fb1[t] : fb2[t - 16];
  __syncthreads();
  const int tr = t >> 4, tc = t & 15;
  float acc[4][3] = {{0.f}};
  #pragma unroll 8
  for (int k = 0; k < 64; ++k) {
    float a[4], b[3];
    #pragma unroll
    for (int i = 0; i < 4; ++i) a[i] = Hs[tr * 4 + i][k];
    #pragma unroll
    for (int j = 0; j < 3; ++j) b[j] = Ws[k][tc * 3 + j];
    #pragma unroll
    for (int i = 0; i < 4; ++i)
      #pragma unroll
      for (int j = 0; j < 3; ++j) acc[i][j] = fmaf(a[i], b[j], acc[i][j]);
  }
  #pragma unroll
  for (int i = 0; i < 4; ++i) {
    int rr = row0 + tr * 4 + i;
    if (rr >= M) continue;
    #pragma unroll
    for (int j = 0; j < 3; ++j) {
      int c = tc * 3 + j;
      float v = acc[i][j] + bs[c];
      if (c < 16) out[(size_t)rr * 16 + c] = v;
      else out[(size_t)M * 16 + (size_t)rr * 32 + (c - 16)] = v;
    }
  }
}

extern "C" void kernel_launch(void* const* d_in, const int* in_sizes, int n_in,
                              void* d_out, int out_size, void* d_ws, size_t ws_size,
                              hipStream_t stream) {
  const float* x    = (const float*)d_in[0];
  const int*   ei   = (const int*)d_in[1];
  const float* ew   = (const float*)d_in[2];
  const float* W1   = (const float*)d_in[3];
  const float* b1   = (const float*)d_in[4];
  const float* W2   = (const float*)d_in[5];
  const float* b2   = (const float*)d_in[6];
  const float* fW1  = (const float*)d_in[7];
  const float* fb1  = (const float*)d_in[8];
  const float* fW2  = (const float*)d_in[9];
  const float* fb2  = (const float*)d_in[10];
  float* out = (float*)d_out;

  const int N = in_sizes[0] / N_FEAT;      // 50000 < 65536 (16-bit src pack)
  const int E = in_sizes[2];
  const int H = (N + 63) & ~63;
  const int* row = ei;
  const int* col = ei + E;

  char* ws = (char*)d_ws;
  float*              dinv = (float*)(ws + 0x000000);              // N f
  int*                cnt  = (int*)  (ws + 0x040000);              // N i
  int*                off  = (int*)  (ws + 0x080000);              // N+1 i
  int*                bsum = (int*)  (ws + 0x0C0000);
  int*                bsum2= (int*)  (ws + 0x0C1000);
  short*              BF1  = (short*)(ws + 0x0C8000);              // 64KB frag-order B1
  short*              BF2  = (short*)(ws + 0x0DA000);              // 8KB frag-order B2
  unsigned long long* hist = (unsigned long long*)(ws + 0x100000); // 8*H u64 (3.2MB)
  int*                cur  = (int*)  (ws + 0x500000);              // 8*H i (1.6MB)
  unsigned*           pairs= (unsigned*)(ws + 0x6C0000);           // E u32 (3.2MB)
  u16*                bufA = (u16*)  (ws + 0xD40000);              // N*64 bf16 (6.4MB)
  u16*                bufB = (u16*)  (ws + 0x1980000);             // N*64 bf16 (6.4MB)

  const int nbN  = (N + 255) / 256;
  const int nbE  = (E + 255) / 256;
  const int nbT  = (N + 15) / 16;          // one wave (16 rows) per block
  const int nbG  = (N + 63) / 64;
  const int nbW  = (N * 64 + 255) / 256;
  const int nH16 = NPART * H / 2;          // hist size in uint4 units
  const int nbZ  = (nH16 + 255) / 256;

  // ---- weight pre-pack into MFMA fragment order (bf16) ----
  k_prepBF<<<32, 256, 0, stream>>>(W1, BF1, N_FEAT);
  k_prepBF<<<2,  256, 0, stream>>>(W2, BF2, N_HID);

  // ---- CSR build (shared by both conv layers) ----
  k_zeroH  <<<nbZ, 256, 0, stream>>>((uint4*)hist, nH16);
  k_degcnt2<<<nbE, 256, 0, stream>>>(col, ew, hist, H, E);
  k_reduce <<<nbN, 256, 0, stream>>>(hist, H, cnt, dinv, N);
  k_scan1  <<<nbN, 256, 0, stream>>>(cnt, off, bsum, N);
  k_scan2  <<<1,   256, 0, stream>>>(bsum, bsum2, nbN);
  k_scan3_initcur<<<nbN, 256, 0, stream>>>(off, bsum2, hist, H, cur, N, E);
  k_fill2  <<<nbE, 256, 0, stream>>>(row, col, ew, dinv, cur, H, pairs, E);

  // ---- layer 1: xw1 = x@W1 (bf16 out); h1 = relu(conv) (bf16) ----
  k_mfma<N_FEAT, false><<<nbT, 64, 0, stream>>>(x, (const short8*)BF1, bufA, N);
  k_gather<true><<<nbW, 256, 0, stream>>>(off, pairs, dinv, bufA, b1, bufB, N);

  // ---- layer 2: xw2 = h1@W2 (bf16 A-path, no cvt); h2 = conv (bf16) ----
  k_mfma<N_HID, true><<<nbT, 64, 0, stream>>>(bufB, (const short8*)BF2, bufA, N);
  k_gather<false><<<nbW, 256, 0, stream>>>(off, pairs, dinv, bufA, b2, bufB, N);

  // ---- FC heads ----
  k_fc<<<nbG, 256, 0, stream>>>(bufB, fW1, fb1, fW2, fb2, out, N);
}

// Round 10
// 196.256 us; speedup vs baseline: 1.2973x; 1.0016x over previous
//
#include <hip/hip_runtime.h>
#include <hip/hip_bf16.h>
#include <cstdint>
#include <cstddef>

#define N_FEAT 512
#define N_HID 64
#define N_CLASS 16
#define N_CLUSTER 32
#define NPART 8          // privatized histogram partitions

typedef short short8 __attribute__((ext_vector_type(8)));
typedef float floatx4 __attribute__((ext_vector_type(4)));
typedef unsigned short u16;
typedef unsigned short u16x4 __attribute__((ext_vector_type(4)));

__device__ __forceinline__ short f2bf(float f) {
  __hip_bfloat16 h = __float2bfloat16(f);   // RNE
  return *reinterpret_cast<short*>(&h);
}
__device__ __forceinline__ u16 f2bfu(float f) { return (u16)f2bf(f); }
__device__ __forceinline__ float bf2f(u16 u) {
  return __uint_as_float((unsigned)u << 16);
}

// ---------------- fast zero-fill ----------------
__global__ void k_zeroH(uint4* __restrict__ p, int n16) {
  int i = blockIdx.x * 256 + threadIdx.x;
  if (i < n16) p[i] = make_uint4(0u, 0u, 0u, 0u);
}

// ---------------- packed degree/count histogram: one u64 atomic per edge ----------------
__global__ void k_degcnt2(const int* __restrict__ col, const float* __restrict__ w,
                          unsigned long long* __restrict__ hist, int H, int E) {
  int e = blockIdx.x * 256 + threadIdx.x;
  if (e >= E) return;
  int p = blockIdx.x & (NPART - 1);
  int c = col[e];
  unsigned long long fx = (unsigned long long)__float2uint_rn(w[e] * 16777216.0f);
  atomicAdd(&hist[(size_t)p * H + c], (1ull << 40) | fx);
}

// ---------------- fold partitions -> cnt, dinv ----------------
__global__ void k_reduce(const unsigned long long* __restrict__ hist, int H,
                         int* __restrict__ cnt, float* __restrict__ dinv, int n) {
  int i = blockIdx.x * 256 + threadIdx.x;
  if (i >= n) return;
  unsigned long long tot = 0;
  #pragma unroll
  for (int p = 0; p < NPART; ++p) tot += hist[(size_t)p * H + i];
  int c = (int)(tot >> 40);
  float wsum = (float)(tot & ((1ull << 40) - 1)) * 5.9604644775390625e-08f; // 2^-24
  cnt[i] = c;
  dinv[i] = rsqrtf(1.0f + wsum);
}

// ---------------- two-level exclusive scan of cnt -> off ----------------
__global__ __launch_bounds__(256) void k_scan1(const int* __restrict__ cnt,
                                               int* __restrict__ off,
                                               int* __restrict__ bsum, int n) {
  __shared__ int sh[256];
  int t = threadIdx.x;
  int i = blockIdx.x * 256 + t;
  int v = (i < n) ? cnt[i] : 0;
  sh[t] = v;
  __syncthreads();
  #pragma unroll
  for (int d = 1; d < 256; d <<= 1) {
    int x = 0;
    if (t >= d) x = sh[t - d];
    __syncthreads();
    if (t >= d) sh[t] += x;
    __syncthreads();
  }
  if (i < n) off[i] = sh[t] - v;
  if (t == 255) bsum[blockIdx.x] = sh[255];
}

__global__ __launch_bounds__(256) void k_scan2(const int* __restrict__ bsum,
                                               int* __restrict__ bsum2, int nb) {
  __shared__ int sh[256];
  int t = threadIdx.x;
  int v = (t < nb) ? bsum[t] : 0;
  sh[t] = v;
  __syncthreads();
  #pragma unroll
  for (int d = 1; d < 256; d <<= 1) {
    int x = 0;
    if (t >= d) x = sh[t - d];
    __syncthreads();
    if (t >= d) sh[t] += x;
    __syncthreads();
  }
  if (t < nb) bsum2[t] = sh[t] - v;
}

__global__ void k_scan3_initcur(int* __restrict__ off, const int* __restrict__ bsum2,
                                const unsigned long long* __restrict__ hist, int H,
                                int* __restrict__ cur, int n, int E) {
  int i = blockIdx.x * 256 + threadIdx.x;
  if (i < n) {
    int o = off[i] + bsum2[blockIdx.x];
    off[i] = o;
    int running = o;
    #pragma unroll
    for (int p = 0; p < NPART; ++p) {
      cur[(size_t)p * H + i] = running;
      running += (int)(hist[(size_t)p * H + i] >> 40);
    }
  }
  if (i == 0) off[n] = E;
}

// ---------------- fill CSR slots: ONE 4B (src16 | coef-bf16) store per edge ----------------
__global__ void k_fill2(const int* __restrict__ rowi, const int* __restrict__ coli,
                        const float* __restrict__ w, const float* __restrict__ dinv,
                        int* __restrict__ cur, int H,
                        unsigned* __restrict__ pairs, int E) {
  int e = blockIdx.x * 256 + threadIdx.x;
  if (e >= E) return;
  int p = blockIdx.x & (NPART - 1);       // must match k_degcnt2's mapping
  int r = rowi[e], c = coli[e];
  int pos = atomicAdd(&cur[(size_t)p * H + c], 1);
  unsigned pk = ((unsigned)r << 16) | (u16)f2bf(dinv[r] * w[e] * dinv[c]);
  pairs[pos] = pk;
}

// ---------------- W[K][64] fp32 -> BF in MFMA-fragment order (bf16) ----------------
// Granule idx = (s*4 + j)*64 + lane holds W[k0..k0+7][col], col = j*16+(lane&15),
// k0 = s*32+(lane>>4)*8: a wave's B-load for (s,j) is a contiguous 1KB read.
__global__ void k_prepBF(const float* __restrict__ W, short* __restrict__ BF, int K) {
  int idx = blockIdx.x * 256 + threadIdx.x;
  int total = (K / 32) * 4 * 64;
  if (idx >= total) return;
  int lane = idx & 63;
  int sj = idx >> 6;
  int j = sj & 3, s = sj >> 2;
  int col = j * 16 + (lane & 15);
  int k0 = s * 32 + ((lane >> 4) << 3);
  short8 v;
  #pragma unroll
  for (int t = 0; t < 8; ++t) v[t] = f2bf(W[(size_t)(k0 + t) * 64 + col]);
  *(short8*)(BF + (size_t)idx * 8) = v;
}

// ---------------- layer-1 MFMA GEMM: C[M,64](bf16) = A[M,512](fp32) @ W ----------------
// 256 thr / 4 waves, 64-row tile. A staged via double-buffered LDS:
//   - global side COALESCED: each 16-lane group reads one 256B row segment
//   - LDS layout XOR-swizzled on BOTH sides: element (row,k4) at slot k4^(row&7)
//     -> ds_read_b128 fragment reads are 2-way max (free)
//   - T14 split: issue global loads early, ds_write after MFMA block, 1 barrier/chunk
// B fragments from BF (contiguous, L2-hot), register double-buffered.
__global__ __launch_bounds__(256, 3) void k_mfma512(
    const float* __restrict__ A, const short8* __restrict__ BF,
    u16* __restrict__ C, int M) {
  __shared__ float As[2][4096];            // 2 x 64 rows x 64 floats = 32 KB
  const int tid = threadIdx.x;
  const int lane = tid & 63;
  const int wid = tid >> 6;
  const int row0 = blockIdx.x * 64;

  // ---- staging map (per thread, per site i=0..3) ----
  // row = i*16 + (tid>>4); slot = tid&15 holds element k4 = slot ^ (row&7)
  const int srow = tid >> 4;               // 0..15
  const int scol4 = (tid & 15) ^ (srow & 7);
  const float* gsrc[4];
  #pragma unroll
  for (int i = 0; i < 4; ++i) {
    int grow = row0 + i * 16 + srow;
    if (grow >= M) grow = M - 1;           // duplicate row; C-write guarded
    gsrc[i] = A + (size_t)grow * 512 + scol4 * 4;
  }
  const int ldsoff = tid * 4;              // float index; byte = tid*16

  // ---- compute-side fragment addresses ----
  const int row_r = wid * 16 + (lane & 15);
  const int xr = row_r & 7;
  const int kqb = (lane >> 4) * 2;         // k4 base within 8-k4 half

  float4 st[4];
  short8 pb[2][8];
  floatx4 acc[4];
  #pragma unroll
  for (int j = 0; j < 4; ++j) acc[j] = (floatx4){0.f, 0.f, 0.f, 0.f};

  // ---- prologue: chunk 0 ----
  #pragma unroll
  for (int i = 0; i < 4; ++i) st[i] = *(const float4*)(gsrc[i]);
  #pragma unroll
  for (int t = 0; t < 8; ++t) pb[0][t] = BF[t * 64 + lane];
  #pragma unroll
  for (int i = 0; i < 4; ++i)
    *(float4*)&As[0][i * 1024 + ldsoff] = st[i];
  __syncthreads();

  #pragma unroll
  for (int c = 0; c < 8; ++c) {
    const int b = c & 1;
    // ---- issue next chunk's loads early (latency hides under MFMA) ----
    if (c + 1 < 8) {
      #pragma unroll
      for (int i = 0; i < 4; ++i)
        st[i] = *(const float4*)(gsrc[i] + (c + 1) * 64);
      #pragma unroll
      for (int t = 0; t < 8; ++t)
        pb[b ^ 1][t] = BF[((c + 1) * 8 + t) * 64 + lane];
      __builtin_amdgcn_sched_barrier(0);   // don't sink loads into MFMA block
    }
    // ---- compute chunk c ----
    const float* rb = &As[b][row_r * 64];
    #pragma unroll
    for (int kq = 0; kq < 2; ++kq) {
      const int k4a = kq * 8 + kqb;
      float4 f0 = *(const float4*)&rb[((k4a)     ^ xr) * 4];
      float4 f1 = *(const float4*)&rb[((k4a + 1) ^ xr) * 4];
      short8 af;
      af[0] = f2bf(f0.x); af[1] = f2bf(f0.y); af[2] = f2bf(f0.z); af[3] = f2bf(f0.w);
      af[4] = f2bf(f1.x); af[5] = f2bf(f1.y); af[6] = f2bf(f1.z); af[7] = f2bf(f1.w);
      acc[0] = __builtin_amdgcn_mfma_f32_16x16x32_bf16(af, pb[b][kq * 4 + 0], acc[0], 0, 0, 0);
      acc[1] = __builtin_amdgcn_mfma_f32_16x16x32_bf16(af, pb[b][kq * 4 + 1], acc[1], 0, 0, 0);
      acc[2] = __builtin_amdgcn_mfma_f32_16x16x32_bf16(af, pb[b][kq * 4 + 2], acc[2], 0, 0, 0);
      acc[3] = __builtin_amdgcn_mfma_f32_16x16x32_bf16(af, pb[b][kq * 4 + 3], acc[3], 0, 0, 0);
    }
    // ---- land next chunk into the other LDS buffer, then fence ----
    if (c + 1 < 8) {
      #pragma unroll
      for (int i = 0; i < 4; ++i)
        *(float4*)&As[b ^ 1][i * 1024 + ldsoff] = st[i];
      __syncthreads();                     // drains vm+lgkm before s_barrier
    }
  }

  const int srowo = row0 + wid * 16 + (lane >> 4) * 4;
  const int scol = lane & 15;
  #pragma unroll
  for (int i = 0; i < 4; ++i) {
    int rr = srowo + i;
    if (rr < M) {
      #pragma unroll
      for (int j = 0; j < 4; ++j)
        C[(size_t)rr * 64 + j * 16 + scol] = f2bfu(acc[j][i]);
    }
  }
}

// ---------------- layer-2 MFMA GEMM (K=64, bf16 A, L2-hot): register version ----------------
__global__ __launch_bounds__(64, 4) void k_mfma64(
    const u16* __restrict__ Av, const short8* __restrict__ BF,
    u16* __restrict__ C, int M) {
  const int lane = threadIdx.x & 63;
  const int rbase = blockIdx.x * 16;
  int r = rbase + (lane & 15);
  if (r >= M) r = M - 1;
  const int klo = (lane >> 4) * 8;
  const u16* arow = Av + (size_t)r * 64 + klo;
  const short8* bbase = BF + lane;

  short8 pah[2];
  short8 pb[2][4];
  pah[0] = *(const short8*)(arow);
  pah[1] = *(const short8*)(arow + 32);
  #pragma unroll
  for (int s = 0; s < 2; ++s)
    #pragma unroll
    for (int j = 0; j < 4; ++j)
      pb[s][j] = bbase[(s * 4 + j) * 64];

  floatx4 acc[4];
  #pragma unroll
  for (int j = 0; j < 4; ++j) acc[j] = (floatx4){0.f, 0.f, 0.f, 0.f};

  #pragma unroll
  for (int s = 0; s < 2; ++s) {
    acc[0] = __builtin_amdgcn_mfma_f32_16x16x32_bf16(pah[s], pb[s][0], acc[0], 0, 0, 0);
    acc[1] = __builtin_amdgcn_mfma_f32_16x16x32_bf16(pah[s], pb[s][1], acc[1], 0, 0, 0);
    acc[2] = __builtin_amdgcn_mfma_f32_16x16x32_bf16(pah[s], pb[s][2], acc[2], 0, 0, 0);
    acc[3] = __builtin_amdgcn_mfma_f32_16x16x32_bf16(pah[s], pb[s][3], acc[3], 0, 0, 0);
  }

  const int srow = rbase + (lane >> 4) * 4;
  const int scol = lane & 15;
  #pragma unroll
  for (int i = 0; i < 4; ++i) {
    int rr = srow + i;
    if (rr < M) {
      #pragma unroll
      for (int j = 0; j < 4; ++j)
        C[(size_t)rr * 64 + j * 16 + scol] = f2bfu(acc[j][i]);
    }
  }
}

// ---------------- gather conv: one wave per node, lane = feature dim ----------------
template<bool RELU>
__global__ __launch_bounds__(256) void k_gather(
    const int* __restrict__ off, const unsigned* __restrict__ pairs,
    const float* __restrict__ dinv,
    const u16* __restrict__ xw, const float* __restrict__ bias,
    u16* __restrict__ h, int n) {
  int gid = blockIdx.x * 256 + threadIdx.x;
  int c = gid >> 6, lane = gid & 63;
  if (c >= n) return;
  float s = dinv[c]; s *= s;
  float acc = fmaf(bf2f(xw[(size_t)c * 64 + lane]), s, bias[lane]);
  int i = off[c], end = off[c + 1];
  for (; i + 7 < end; i += 8) {
    unsigned p[8];
    float v[8];
    #pragma unroll
    for (int t = 0; t < 8; ++t) p[t] = pairs[i + t];
    #pragma unroll
    for (int t = 0; t < 8; ++t)
      v[t] = bf2f(xw[(size_t)(p[t] >> 16) * 64 + lane]);
    #pragma unroll
    for (int t = 0; t < 8; ++t)
      acc = fmaf(v[t], __uint_as_float((p[t] & 0xffffu) << 16), acc);
  }
  for (; i + 1 < end; i += 2) {
    unsigned p0 = pairs[i], p1 = pairs[i + 1];
    float v0 = bf2f(xw[(size_t)(p0 >> 16) * 64 + lane]);
    float v1 = bf2f(xw[(size_t)(p1 >> 16) * 64 + lane]);
    acc = fmaf(v0, __uint_as_float((p0 & 0xffffu) << 16), acc);
    acc = fmaf(v1, __uint_as_float((p1 & 0xffffu) << 16), acc);
  }
  if (i < end) {
    unsigned p = pairs[i];
    acc = fmaf(bf2f(xw[(size_t)(p >> 16) * 64 + lane]),
               __uint_as_float((p & 0xffffu) << 16), acc);
  }
  if (RELU) acc = fmaxf(acc, 0.f);
  h[(size_t)c * 64 + lane] = f2bfu(acc);
}

// ---------------- fused FC head (h in bf16) ----------------
__global__ __launch_bounds__(256) void k_fc(
    const u16* __restrict__ h,
    const float* __restrict__ fW1, const float* __restrict__ fb1,
    const float* __restrict__ fW2, const float* __restrict__ fb2,
    float* __restrict__ out, int M) {
  __shared__ float Hs[64][68];
  __shared__ float Ws[64][48];
  __shared__ float bs[48];
  const int t = threadIdx.x;
  const int row0 = blockIdx.x * 64;
  #pragma unroll
  for (int i = 0; i < 4; ++i) {
    int f = t + i * 256;
    int r = f >> 4, k4 = f & 15;
    int rr = row0 + r;
    float4 v = make_float4(0.f, 0.f, 0.f, 0.f);
    if (rr < M) {
      u16x4 u = *(const u16x4*)&h[(size_t)rr * 64 + k4 * 4];
      v = make_float4(bf2f(u[0]), bf2f(u[1]), bf2f(u[2]), bf2f(u[3]));
    }
    *(float4*)&Hs[r][k4 * 4] = v;
  }
  for (int f = t; f < 64 * 48; f += 256) {
    int k = f / 48, c = f - k * 48;
    Ws[k][c] = (c < 16) ? fW1[k * 16 + c] : fW2[k * 32 + (c - 16)];
  }
  if (t < 48) bs[t] = (t < 16) ? fb1[t] : fb2[t - 16];
  __syncthreads();
  const int tr = t >> 4, tc = t & 15;
  float acc[4][3] = {{0.f}};
  #pragma unroll 8
  for (int k = 0; k < 64; ++k) {
    float a[4], b[3];
    #pragma unroll
    for (int i = 0; i < 4; ++i) a[i] = Hs[tr * 4 + i][k];
    #pragma unroll
    for (int j = 0; j < 3; ++j) b[j] = Ws[k][tc * 3 + j];
    #pragma unroll
    for (int i = 0; i < 4; ++i)
      #pragma unroll
      for (int j = 0; j < 3; ++j) acc[i][j] = fmaf(a[i], b[j], acc[i][j]);
  }
  #pragma unroll
  for (int i = 0; i < 4; ++i) {
    int rr = row0 + tr * 4 + i;
    if (rr >= M) continue;
    #pragma unroll
    for (int j = 0; j < 3; ++j) {
      int c = tc * 3 + j;
      float v = acc[i][j] + bs[c];
      if (c < 16) out[(size_t)rr * 16 + c] = v;
      else out[(size_t)M * 16 + (size_t)rr * 32 + (c - 16)] = v;
    }
  }
}

extern "C" void kernel_launch(void* const* d_in, const int* in_sizes, int n_in,
                              void* d_out, int out_size, void* d_ws, size_t ws_size,
                              hipStream_t stream) {
  const float* x    = (const float*)d_in[0];
  const int*   ei   = (const int*)d_in[1];
  const float* ew   = (const float*)d_in[2];
  const float* W1   = (const float*)d_in[3];
  const float* b1   = (const float*)d_in[4];
  const float* W2   = (const float*)d_in[5];
  const float* b2   = (const float*)d_in[6];
  const float* fW1  = (const float*)d_in[7];
  const float* fb1  = (const float*)d_in[8];
  const float* fW2  = (const float*)d_in[9];
  const float* fb2  = (const float*)d_in[10];
  float* out = (float*)d_out;

  const int N = in_sizes[0] / N_FEAT;      // 50000 < 65536 (16-bit src pack)
  const int E = in_sizes[2];
  const int H = (N + 63) & ~63;
  const int* row = ei;
  const int* col = ei + E;

  char* ws = (char*)d_ws;
  float*              dinv = (float*)(ws + 0x000000);              // N f
  int*                cnt  = (int*)  (ws + 0x040000);              // N i
  int*                off  = (int*)  (ws + 0x080000);              // N+1 i
  int*                bsum = (int*)  (ws + 0x0C0000);
  int*                bsum2= (int*)  (ws + 0x0C1000);
  short*              BF1  = (short*)(ws + 0x0C8000);              // 64KB frag-order B1
  short*              BF2  = (short*)(ws + 0x0DA000);              // 8KB frag-order B2
  unsigned long long* hist = (unsigned long long*)(ws + 0x100000); // 8*H u64 (3.2MB)
  int*                cur  = (int*)  (ws + 0x500000);              // 8*H i (1.6MB)
  unsigned*           pairs= (unsigned*)(ws + 0x6C0000);           // E u32 (3.2MB)
  u16*                bufA = (u16*)  (ws + 0xD40000);              // N*64 bf16 (6.4MB)
  u16*                bufB = (u16*)  (ws + 0x1980000);             // N*64 bf16 (6.4MB)

  const int nbN  = (N + 255) / 256;
  const int nbE  = (E + 255) / 256;
  const int nbS  = (N + 63) / 64;          // 64-row staged-GEMM blocks
  const int nbT  = (N + 15) / 16;          // 16-row register-GEMM blocks
  const int nbG  = (N + 63) / 64;
  const int nbW  = (N * 64 + 255) / 256;
  const int nH16 = NPART * H / 2;          // hist size in uint4 units
  const int nbZ  = (nH16 + 255) / 256;

  // ---- weight pre-pack into MFMA fragment order (bf16) ----
  k_prepBF<<<32, 256, 0, stream>>>(W1, BF1, N_FEAT);
  k_prepBF<<<2,  256, 0, stream>>>(W2, BF2, N_HID);

  // ---- CSR build (shared by both conv layers) ----
  k_zeroH  <<<nbZ, 256, 0, stream>>>((uint4*)hist, nH16);
  k_degcnt2<<<nbE, 256, 0, stream>>>(col, ew, hist, H, E);
  k_reduce <<<nbN, 256, 0, stream>>>(hist, H, cnt, dinv, N);
  k_scan1  <<<nbN, 256, 0, stream>>>(cnt, off, bsum, N);
  k_scan2  <<<1,   256, 0, stream>>>(bsum, bsum2, nbN);
  k_scan3_initcur<<<nbN, 256, 0, stream>>>(off, bsum2, hist, H, cur, N, E);
  k_fill2  <<<nbE, 256, 0, stream>>>(row, col, ew, dinv, cur, H, pairs, E);

  // ---- layer 1: xw1 = x@W1 (LDS-staged MFMA); h1 = relu(conv) ----
  k_mfma512<<<nbS, 256, 0, stream>>>(x, (const short8*)BF1, bufA, N);
  k_gather<true><<<nbW, 256, 0, stream>>>(off, pairs, dinv, bufA, b1, bufB, N);

  // ---- layer 2: xw2 = h1@W2 (register MFMA, bf16 A); h2 = conv ----
  k_mfma64<<<nbT, 64, 0, stream>>>(bufB, (const short8*)BF2, bufA, N);
  k_gather<false><<<nbW, 256, 0, stream>>>(off, pairs, dinv, bufA, b2, bufB, N);

  // ---- FC heads ----
  k_fc<<<nbG, 256, 0, stream>>>(bufB, fW1, fb1, fW2, fb2, out, N);
}